// Round 6
// baseline (537.915 us; speedup 1.0000x reference)
//
#include <hip/hip_runtime.h>
#include <math.h>

// ---- problem constants (structural, from setup_inputs) ----
#define NG    32          // graphs
#define NPG   512         // nodes per graph
#define NN    16384       // N
#define DEG   32          // edges per node (dst-sorted: node i owns edges [32i,32i+32))
#define NE    524288      // E
#define EPG   16384       // edges per graph
#define DD    128
#define HIDN  256
#define NEXPT 8
#define EHID  64
#define NL    3

typedef __attribute__((ext_vector_type(8))) short bh8;   // 8 bf16 = 4 VGPRs (MFMA A/B frag)
typedef __attribute__((ext_vector_type(4))) float f4;    // MFMA C/D frag

// round-to-nearest-even f32 -> bf16
__device__ __forceinline__ unsigned short bf16_1(float x) {
  unsigned int u = __float_as_uint(x);
  return (unsigned short)((u + 0x7fffu + ((u >> 16) & 1u)) >> 16);
}
__device__ __forceinline__ unsigned int bf16pair(float a, float b) {
  return (unsigned int)bf16_1(a) | ((unsigned int)bf16_1(b) << 16);
}

// =============== utility ===============
__global__ void k_zero(float4* p, int n4) {
  int i = blockIdx.x * 256 + threadIdx.x;
  if (i < n4) p[i] = make_float4(0.f, 0.f, 0.f, 0.f);
}

// transpose one [M][N] f32 matrix per blockIdx.z -> [N][M] bf16
__global__ void k_tr(const float* __restrict__ in, unsigned short* __restrict__ outp,
                     int M, int N) {
  __shared__ float tile[32][33];
  const float* ip = in + (size_t)blockIdx.z * M * N;
  unsigned short* op = outp + (size_t)blockIdx.z * M * N;
  int t = threadIdx.x;
  int i = t >> 5, j = t & 31;
  int c0 = blockIdx.x * 32, r0 = blockIdx.y * 32;
#pragma unroll
  for (int p = 0; p < 4; ++p)
    tile[i + 8 * p][j] = ip[(size_t)(r0 + i + 8 * p) * N + c0 + j];
  __syncthreads();
#pragma unroll
  for (int p = 0; p < 4; ++p)
    op[(size_t)(c0 + i + 8 * p) * M + r0 + j] = bf16_1(tile[j][i + 8 * p]);
}

// =============== dist + per-graph sum / sumsq ===============
__global__ void k_dist(const float* __restrict__ pos, const int* __restrict__ src,
                       const int* __restrict__ dst, float* __restrict__ dist,
                       float* __restrict__ gsum, float* __restrict__ gsq) {
  int e = blockIdx.x * 256 + threadIdx.x;
  int s = src[e], t = dst[e];
  float dx = pos[3 * s]     - pos[3 * t];
  float dy = pos[3 * s + 1] - pos[3 * t + 1];
  float dz = pos[3 * s + 2] - pos[3 * t + 2];
  float d = sqrtf(dx * dx + dy * dy + dz * dz);
  dist[e] = d;
  float s1 = d, s2 = d * d;
  for (int o = 32; o; o >>= 1) { s1 += __shfl_down(s1, o); s2 += __shfl_down(s2, o); }
  __shared__ float r1[4], r2[4];
  int w = threadIdx.x >> 6;
  if ((threadIdx.x & 63) == 0) { r1[w] = s1; r2[w] = s2; }
  __syncthreads();
  if (threadIdx.x == 0) {
    int g = e >> 14;
    atomicAdd(&gsum[g], r1[0] + r1[1] + r1[2] + r1[3]);
    atomicAdd(&gsq[g],  r2[0] + r2[1] + r2[2] + r2[3]);
  }
}

__global__ void k_efin(const float* __restrict__ gsum, const float* __restrict__ gsq,
                       const float* __restrict__ dnw, const float* __restrict__ dnb,
                       const float* __restrict__ dnms, float* __restrict__ ga, float* __restrict__ gb) {
  int g = threadIdx.x;
  if (g < NG) {
    float ms = dnms[0];
    float mean = gsum[g] * (1.f / EPG);
    float var = gsq[g] * (1.f / EPG) - (2.f * ms - ms * ms) * mean * mean;
    float a = dnw[0] * rsqrtf(var + 1e-5f);
    ga[g] = a;
    gb[g] = dnb[0] - a * ms * mean;
  }
}

__global__ void k_embed(const float4* __restrict__ emb, const int* __restrict__ at,
                        float4* __restrict__ h) {
  int gid = blockIdx.x * 256 + threadIdx.x;
  int i = gid >> 5, q = gid & 31;
  h[gid] = emb[at[i] * 32 + q];
}

// =============== per-layer edge MoE router ===============
__global__ void k_edge(const float* __restrict__ dist,
                       const float* __restrict__ ga, const float* __restrict__ gb,
                       const float* __restrict__ ew1, const float* __restrict__ eb1,
                       const float* __restrict__ ew2, const float* __restrict__ eb2,
                       float* __restrict__ eaw, float* __restrict__ part) {
  __shared__ float w1s[EHID], b1s[EHID];
  __shared__ __align__(16) float w2s[EHID * NEXPT];
  __shared__ float b2s[NEXPT];
  int t = threadIdx.x;
  if (t < EHID) { w1s[t] = ew1[t]; b1s[t] = eb1[t]; }
  if (t < NEXPT) b2s[t] = eb2[t];
  for (int j = t; j < EHID * NEXPT; j += 256) w2s[j] = ew2[j];
  __syncthreads();

  int e0 = blockIdx.x * 1024 + t * 4;
  float4 dv = *(const float4*)&dist[e0];
  float dd[4] = {dv.x, dv.y, dv.z, dv.w};
  int g = e0 >> 14;
  float gav = ga[g], gbv = gb[g];
  float a0[4], ewv[4];
#pragma unroll
  for (int j = 0; j < 4; ++j) {
    a0[j] = gav * dd[j] + gbv;
    ewv[j] = (10.0f - dd[j]) * 0.1f;
  }
  float acc[4][NEXPT];
#pragma unroll
  for (int j = 0; j < 4; ++j)
#pragma unroll
    for (int x = 0; x < NEXPT; ++x) acc[j][x] = b2s[x];

  for (int k = 0; k < EHID; ++k) {
    float w1k = w1s[k], b1k = b1s[k];
    float hk[4];
#pragma unroll
    for (int j = 0; j < 4; ++j) hk[j] = fmaxf(a0[j] * w1k + b1k, 0.f);
    float4 wa = *(const float4*)&w2s[k * 8];
    float4 wb = *(const float4*)&w2s[k * 8 + 4];
    float ww[8] = {wa.x, wa.y, wa.z, wa.w, wb.x, wb.y, wb.z, wb.w};
#pragma unroll
    for (int j = 0; j < 4; ++j)
#pragma unroll
      for (int x = 0; x < NEXPT; ++x) acc[j][x] += hk[j] * ww[x];
  }

  float esum[NEXPT] = {0, 0, 0, 0, 0, 0, 0, 0};
#pragma unroll
  for (int j = 0; j < 4; ++j) {
    float m = acc[j][0];
#pragma unroll
    for (int x = 1; x < NEXPT; ++x) m = fmaxf(m, acc[j][x]);
    float p[NEXPT], s = 0.f;
#pragma unroll
    for (int x = 0; x < NEXPT; ++x) { p[x] = __expf(acc[j][x] - m); s += p[x]; }
    float inv = 1.f / s;
    float fw = ewv[j] * inv;
    float4 o0 = {p[0] * fw, p[1] * fw, p[2] * fw, p[3] * fw};
    float4 o1 = {p[4] * fw, p[5] * fw, p[6] * fw, p[7] * fw};
    *(float4*)&eaw[(size_t)(e0 + j) * 8]     = o0;
    *(float4*)&eaw[(size_t)(e0 + j) * 8 + 4] = o1;
#pragma unroll
    for (int x = 0; x < NEXPT; ++x) esum[x] += p[x] * inv;
  }
  for (int o = 32; o; o >>= 1)
#pragma unroll
    for (int x = 0; x < NEXPT; ++x) esum[x] += __shfl_down(esum[x], o);
  __shared__ float ps[4][NEXPT];
  int w = t >> 6;
  if ((t & 63) == 0)
#pragma unroll
    for (int x = 0; x < NEXPT; ++x) ps[w][x] = esum[x];
  __syncthreads();
  if (t < NEXPT) part[blockIdx.x * NEXPT + t] = ps[0][t] + ps[1][t] + ps[2][t] + ps[3][t];
}

// =============== aggregation -> bf16 agg[x][i][k] ===============
// grid NN/8, block 256: 32-thread slice per node (lane = 4-dim chunk).
// Each thread reads each gathered h float4 ONCE and applies all 8 expert
// weights in registers (fixes the 8x redundant L1 traffic of the old layout).
__global__ __launch_bounds__(256) void k_agg(const float* __restrict__ h, const int* __restrict__ src,
                      const float* __restrict__ eaw, unsigned short* __restrict__ agg) {
  const int t = threadIdx.x;
  const int s = t >> 5;       // node slice 0..7
  const int lane = t & 31;    // dim chunk (4 floats)
  const int i = blockIdx.x * 8 + s;
  __shared__ int ssrc[8][DEG];
  __shared__ __align__(16) float sw[8][DEG][NEXPT];  // [slice][edge][expert]
  const int e0b = blockIdx.x * 8 * DEG;
  ssrc[s][lane] = src[e0b + t];
  {
    const float4* ep = (const float4*)&eaw[(size_t)e0b * 8];  // 512 float4
    float4* sp = (float4*)&sw[0][0][0];
    sp[t] = ep[t];
    sp[t + 256] = ep[t + 256];
  }
  __syncthreads();
  f4 acc[NEXPT];
#pragma unroll
  for (int x = 0; x < NEXPT; ++x) acc[x] = (f4)0.f;
#pragma unroll 2
  for (int k = 0; k < DEG; ++k) {
    f4 hv = *(const f4*)&h[(size_t)ssrc[s][k] * 128 + lane * 4];
    f4 w0 = *(const f4*)&sw[s][k][0];   // broadcast within slice
    f4 w1 = *(const f4*)&sw[s][k][4];
    float ww[8] = {w0[0], w0[1], w0[2], w0[3], w1[0], w1[1], w1[2], w1[3]};
#pragma unroll
    for (int x = 0; x < NEXPT; ++x) acc[x] += ww[x] * hv;
  }
#pragma unroll
  for (int x = 0; x < NEXPT; ++x) {
    uint2 pk;
    pk.x = bf16pair(acc[x][0], acc[x][1]);
    pk.y = bf16pair(acc[x][2], acc[x][3]);
    *(uint2*)&agg[((size_t)x * NN + i) * 128 + lane * 4] = pk;
  }
}

// =============== MFMA expert MLP ===============
// 32-node tile (grid NN/32 = 512 blocks = 2 blocks/CU for latency overlap),
// hid double-buffered -> ONE barrier per expert (wave at barrier x has finished
// GEMM2 of expert x-1, so buffer (x&1) is free to overwrite).
//   GEMM1: D1[h][n] = W1T(256x128) x aggT(128x32)   (frags straight from global bf16)
//   GEMM2: D2[d][n] = W2T(128x256) x hidT(256x32)   (hid in XOR-swizzled LDS)
// mfma_f32_16x16x32_bf16 mapping (m89): A[m=l&15][k=(l>>4)*8+j], B[k][n=l&15], D[m=(l>>4)*4+r][n=l&15]
__global__ __launch_bounds__(256) void k_mlp(
    const unsigned short* __restrict__ agg,  // [8][NN][128] bf16
    const unsigned short* __restrict__ w1t,  // [8][256][128] bf16  (h-major, k contig)
    const float* __restrict__ b1g,           // [8][256]
    const unsigned short* __restrict__ w2t,  // [8][128][256] bf16  (d-major, h contig)
    const float* __restrict__ b2g,           // [8][128]
    float* __restrict__ out) {               // [NN][128]
  __shared__ unsigned short hid[2][32 * 256];  // [buf][node][h] bf16, byte ^= (node&7)<<4
  char* hb = (char*)hid;
  const int t = threadIdx.x;
  const int w = t >> 6;       // wave 0..3
  const int l15 = t & 15;
  const int q = (t & 63) >> 4;  // 0..3
  const int i0 = blockIdx.x * 32;

  f4 acc2[2][2];
#pragma unroll
  for (int dt = 0; dt < 2; ++dt)
#pragma unroll
    for (int nt = 0; nt < 2; ++nt) acc2[dt][nt] = (f4)0.f;

  for (int x = 0; x < NEXPT; ++x) {
    const int bufb = (x & 1) * 16384;  // byte offset of current hid buffer
    // ---- GEMM1: wave w covers h in [64w, 64w+64) ----
    f4 acc1[4][2];
#pragma unroll
    for (int ht = 0; ht < 4; ++ht) {
      f4 bb = *(const f4*)&b1g[x * 256 + 64 * w + 16 * ht + 4 * q];
#pragma unroll
      for (int nt = 0; nt < 2; ++nt) acc1[ht][nt] = bb;
    }
#pragma unroll
    for (int ks = 0; ks < 4; ++ks) {
      bh8 afr[4], bfr[2];
#pragma unroll
      for (int ht = 0; ht < 4; ++ht)
        afr[ht] = *(const bh8*)&w1t[((size_t)x * 256 + 64 * w + 16 * ht + l15) * 128 + ks * 32 + q * 8];
#pragma unroll
      for (int nt = 0; nt < 2; ++nt)
        bfr[nt] = *(const bh8*)&agg[((size_t)x * NN + i0 + 16 * nt + l15) * 128 + ks * 32 + q * 8];
#pragma unroll
      for (int ht = 0; ht < 4; ++ht)
#pragma unroll
        for (int nt = 0; nt < 2; ++nt)
          acc1[ht][nt] = __builtin_amdgcn_mfma_f32_16x16x32_bf16(afr[ht], bfr[nt], acc1[ht][nt], 0, 0, 0);
    }
    // relu + pack 2x bf16 -> swizzled LDS buffer (x&1)
#pragma unroll
    for (int ht = 0; ht < 4; ++ht)
#pragma unroll
      for (int nt = 0; nt < 2; ++nt) {
        int node = 16 * nt + l15;
        int h0 = 64 * w + 16 * ht + 4 * q;
        int byte0 = bufb + ((node * 512 + h0 * 2) ^ ((node & 7) << 4));
        *(unsigned int*)(hb + byte0) =
            bf16pair(fmaxf(acc1[ht][nt][0], 0.f), fmaxf(acc1[ht][nt][1], 0.f));
        *(unsigned int*)(hb + byte0 + 4) =
            bf16pair(fmaxf(acc1[ht][nt][2], 0.f), fmaxf(acc1[ht][nt][3], 0.f));
      }
    __syncthreads();  // hid[x&1] ready for all waves
    // ---- GEMM2: wave w covers d in [32w, 32w+32) ----
#pragma unroll
    for (int ks = 0; ks < 8; ++ks) {
      bh8 a2[2], b2f[2];
#pragma unroll
      for (int dt = 0; dt < 2; ++dt)
        a2[dt] = *(const bh8*)&w2t[((size_t)x * 128 + 32 * w + 16 * dt + l15) * 256 + ks * 32 + q * 8];
#pragma unroll
      for (int nt = 0; nt < 2; ++nt) {
        int node = 16 * nt + l15;
        int byte0 = bufb + ((node * 512 + ks * 64 + q * 16) ^ ((node & 7) << 4));
        b2f[nt] = *(const bh8*)(hb + byte0);
      }
#pragma unroll
      for (int dt = 0; dt < 2; ++dt)
#pragma unroll
        for (int nt = 0; nt < 2; ++nt)
          acc2[dt][nt] = __builtin_amdgcn_mfma_f32_16x16x32_bf16(a2[dt], b2f[nt], acc2[dt][nt], 0, 0, 0);
    }
    // + b2 (per expert)
#pragma unroll
    for (int dt = 0; dt < 2; ++dt) {
      f4 bb = *(const f4*)&b2g[x * 128 + 32 * w + 16 * dt + 4 * q];
#pragma unroll
      for (int nt = 0; nt < 2; ++nt) acc2[dt][nt] += bb;
    }
  }
  // store: lane holds d = 32w+16dt+4q+r (contiguous 4), node = 16nt+l15
#pragma unroll
  for (int dt = 0; dt < 2; ++dt)
#pragma unroll
    for (int nt = 0; nt < 2; ++nt)
      *(f4*)&out[(size_t)(i0 + 16 * nt + l15) * 128 + 32 * w + 16 * dt + 4 * q] = acc2[dt][nt];
}

// =============== node GraphNorm ===============
__global__ void k_gnr(const float* __restrict__ h, float* __restrict__ nsum, float* __restrict__ nsq) {
  int g = blockIdx.x, strip = blockIdx.y;
  int c = threadIdx.x;
  const float* base = h + ((size_t)g * NPG + strip * 64) * 128 + c;
  float s = 0.f, q = 0.f;
  for (int n = 0; n < 64; ++n) { float v = base[(size_t)n * 128]; s += v; q += v * v; }
  atomicAdd(&nsum[g * 128 + c], s);
  atomicAdd(&nsq[g * 128 + c], q);
}

__global__ void k_gnf(const float* __restrict__ nsum, const float* __restrict__ nsq,
                      const float* __restrict__ gw, const float* __restrict__ gbv,
                      const float* __restrict__ gms, float* __restrict__ amul, float* __restrict__ aadd) {
  int idx = blockIdx.x * 256 + threadIdx.x;
  int c = idx & 127;
  float ms = gms[c];
  float mean = nsum[idx] * (1.f / NPG);
  float var = nsq[idx] * (1.f / NPG) - (2.f * ms - ms * ms) * mean * mean;
  float a = gw[c] * rsqrtf(var + 1e-5f);
  amul[idx] = a;
  aadd[idx] = gbv[c] - a * ms * mean;
}

__global__ void k_gna(float* __restrict__ h, const float* __restrict__ amul,
                      const float* __restrict__ aadd) {
  int gid = blockIdx.x * 256 + threadIdx.x;
  int i = gid >> 5, q = gid & 31;
  int g = i >> 9;
  float4 v = *(float4*)&h[(size_t)gid * 4];
  float4 a = *(const float4*)&amul[g * 128 + q * 4];
  float4 b = *(const float4*)&aadd[g * 128 + q * 4];
  v.x = tanhf(a.x * v.x + b.x);
  v.y = tanhf(a.y * v.y + b.y);
  v.z = tanhf(a.z * v.z + b.z);
  v.w = tanhf(a.w * v.w + b.w);
  *(float4*)&h[(size_t)gid * 4] = v;
}

// =============== final pooling + routing loss ===============
__global__ void k_pool(const float* __restrict__ h, float* __restrict__ outp) {
  int g = blockIdx.x, t = threadIdx.x;
  const float4* base = (const float4*)(h + (size_t)g * NPG * 128);
  float s = 0.f;
  for (int p = 0; p < 64; ++p) { float4 v = base[p * 256 + t]; s += v.x + v.y + v.z + v.w; }
  for (int o = 32; o; o >>= 1) s += __shfl_down(s, o);
  __shared__ float r[4];
  if ((t & 63) == 0) r[t >> 6] = s;
  __syncthreads();
  if (t == 0) outp[g] = (r[0] + r[1] + r[2] + r[3]) * (1.f / (NPG * 128));
}

__global__ void k_lbl(const float* __restrict__ part, float* __restrict__ outp) {
  __shared__ float s[NL * NEXPT];
  int t = threadIdx.x;
  if (t < NL * NEXPT) {
    int l = t >> 3, x = t & 7;
    float acc = 0.f;
    for (int b = 0; b < 512; ++b) acc += part[(size_t)(l * 512 + b) * NEXPT + x];
    s[t] = acc;
  }
  __syncthreads();
  if (t == 0) {
    float lbl = 0.f;
    for (int j = 0; j < NL * NEXPT; ++j) { float m = s[j] * (1.f / NE); lbl += m * m; }
    outp[0] = lbl * ((float)NEXPT / NL) * 0.1f;
  }
}

// =============== launcher ===============
extern "C" void kernel_launch(void* const* d_in, const int* in_sizes, int n_in,
                              void* d_out, int out_size, void* d_ws, size_t ws_size,
                              hipStream_t stream) {
  (void)in_sizes; (void)n_in; (void)out_size; (void)ws_size;
  const float* pos  = (const float*)d_in[0];
  const float* emb  = (const float*)d_in[1];
  const float* ew1  = (const float*)d_in[2];
  const float* eb1  = (const float*)d_in[3];
  const float* ew2  = (const float*)d_in[4];
  const float* eb2  = (const float*)d_in[5];
  const float* nw1  = (const float*)d_in[6];
  const float* nb1  = (const float*)d_in[7];
  const float* nw2  = (const float*)d_in[8];
  const float* nb2  = (const float*)d_in[9];
  const float* gnw  = (const float*)d_in[10];
  const float* gnb  = (const float*)d_in[11];
  const float* gnms = (const float*)d_in[12];
  const float* dnw  = (const float*)d_in[13];
  const float* dnb  = (const float*)d_in[14];
  const float* dnms = (const float*)d_in[15];
  const int* atom   = (const int*)d_in[16];
  const int* eidx   = (const int*)d_in[17];
  float* out = (float*)d_out;

  char* wsb = (char*)d_ws;
  float* dist = (float*)wsb;                 wsb += sizeof(float) * NE;
  float* eaw  = (float*)wsb;                 wsb += sizeof(float) * (size_t)NE * 8;
  unsigned short* aggb = (unsigned short*)wsb; wsb += sizeof(short) * (size_t)8 * NN * 128;
  unsigned short* w1t  = (unsigned short*)wsb; wsb += sizeof(short) * (size_t)NL * 8 * 256 * 128;
  unsigned short* w2t  = (unsigned short*)wsb; wsb += sizeof(short) * (size_t)NL * 8 * 256 * 128;
  float* hA   = (float*)wsb;                 wsb += sizeof(float) * (size_t)NN * 128;
  float* hB   = (float*)wsb;                 wsb += sizeof(float) * (size_t)NN * 128;
  float* gsum = (float*)wsb;                 wsb += sizeof(float) * NG;
  float* gsq  = (float*)wsb;                 wsb += sizeof(float) * NG;
  float* ga   = (float*)wsb;                 wsb += sizeof(float) * NG;
  float* gb   = (float*)wsb;                 wsb += sizeof(float) * NG;
  float* nsum = (float*)wsb;                 wsb += sizeof(float) * NG * 128;
  float* nsq  = (float*)wsb;                 wsb += sizeof(float) * NG * 128;
  float* amul = (float*)wsb;                 wsb += sizeof(float) * NG * 128;
  float* aadd = (float*)wsb;                 wsb += sizeof(float) * NG * 128;
  float* part = (float*)wsb;                 wsb += sizeof(float) * (size_t)NL * 512 * NEXPT;

  const int* srcA = eidx;
  const int* dstA = eidx + NE;

  k_zero<<<1, 256, 0, stream>>>((float4*)gsum, 16);  // gsum+gsq
  // pre-transpose weights to bf16: w1t[l,x][h][k], w2t[l,x][d][h]
  {
    dim3 g1(HIDN / 32, DD / 32, NL * NEXPT);
    k_tr<<<g1, 256, 0, stream>>>(nw1, w1t, DD, HIDN);
    dim3 g2(DD / 32, HIDN / 32, NL * NEXPT);
    k_tr<<<g2, 256, 0, stream>>>(nw2, w2t, HIDN, DD);
  }
  k_dist<<<NE / 256, 256, 0, stream>>>(pos, srcA, dstA, dist, gsum, gsq);
  k_efin<<<1, 64, 0, stream>>>(gsum, gsq, dnw, dnb, dnms, ga, gb);
  k_embed<<<NN * 32 / 256, 256, 0, stream>>>((const float4*)emb, atom, (float4*)hA);

  float* hcur = hA;
  float* hnxt = hB;
  for (int l = 0; l < NL; ++l) {
    k_edge<<<NE / 1024, 256, 0, stream>>>(dist, ga, gb, ew1 + l * EHID, eb1 + l * EHID,
                                          ew2 + (size_t)l * EHID * NEXPT, eb2 + l * NEXPT,
                                          eaw, part + (size_t)l * 512 * NEXPT);
    k_agg<<<NN / 8, 256, 0, stream>>>(hcur, srcA, eaw, aggb);
    k_mlp<<<NN / 32, 256, 0, stream>>>(aggb,
                                       w1t + (size_t)l * 8 * 256 * 128,
                                       nb1 + (size_t)l * 8 * 256,
                                       w2t + (size_t)l * 8 * 256 * 128,
                                       nb2 + (size_t)l * 8 * 128, hnxt);
    if (l + 1 < NL) {
      k_zero<<<8, 256, 0, stream>>>((float4*)nsum, 2048);  // nsum+nsq
      dim3 gr(NG, 8);
      k_gnr<<<gr, 128, 0, stream>>>(hnxt, nsum, nsq);
      k_gnf<<<16, 256, 0, stream>>>(nsum, nsq, gnw + l * 128, gnb + l * 128, gnms + l * 128,
                                    amul, aadd);
      k_gna<<<NN * 32 / 256, 256, 0, stream>>>(hnxt, amul, aadd);
    }
    float* tmp = hcur; hcur = hnxt; hnxt = tmp;
  }
  k_pool<<<NG, 256, 0, stream>>>(hcur, out);
  k_lbl<<<1, 64, 0, stream>>>(part, out + NG);
}

// Round 9
// 508.850 us; speedup vs baseline: 1.0571x; 1.0571x over previous
//
#include <hip/hip_runtime.h>
#include <math.h>

// ---- problem constants (structural, from setup_inputs) ----
#define NG    32          // graphs
#define NPG   512         // nodes per graph
#define NN    16384       // N
#define DEG   32          // edges per node (dst-sorted: node i owns edges [32i,32i+32))
#define NE    524288      // E
#define EPG   16384       // edges per graph
#define DD    128
#define HIDN  256
#define NEXPT 8
#define EHID  64
#define NL    3

typedef __attribute__((ext_vector_type(8))) short bh8;   // 8 bf16 = 4 VGPRs (MFMA A/B frag)
typedef __attribute__((ext_vector_type(4))) float f4;    // MFMA C/D frag

// round-to-nearest-even f32 -> bf16
__device__ __forceinline__ unsigned short bf16_1(float x) {
  unsigned int u = __float_as_uint(x);
  return (unsigned short)((u + 0x7fffu + ((u >> 16) & 1u)) >> 16);
}
__device__ __forceinline__ unsigned int bf16pair(float a, float b) {
  return (unsigned int)bf16_1(a) | ((unsigned int)bf16_1(b) << 16);
}

// =============== utility ===============
__global__ void k_zero(float4* p, int n4) {
  int i = blockIdx.x * 256 + threadIdx.x;
  if (i < n4) p[i] = make_float4(0.f, 0.f, 0.f, 0.f);
}

// transpose one [M][N] f32 matrix per blockIdx.z -> [N][M] bf16
__global__ void k_tr(const float* __restrict__ in, unsigned short* __restrict__ outp,
                     int M, int N) {
  __shared__ float tile[32][33];
  const float* ip = in + (size_t)blockIdx.z * M * N;
  unsigned short* op = outp + (size_t)blockIdx.z * M * N;
  int t = threadIdx.x;
  int i = t >> 5, j = t & 31;
  int c0 = blockIdx.x * 32, r0 = blockIdx.y * 32;
#pragma unroll
  for (int p = 0; p < 4; ++p)
    tile[i + 8 * p][j] = ip[(size_t)(r0 + i + 8 * p) * N + c0 + j];
  __syncthreads();
#pragma unroll
  for (int p = 0; p < 4; ++p)
    op[(size_t)(c0 + i + 8 * p) * M + r0 + j] = bf16_1(tile[j][i + 8 * p]);
}

// =============== dist + per-graph sum / sumsq ===============
__global__ void k_dist(const float* __restrict__ pos, const int* __restrict__ src,
                       const int* __restrict__ dst, float* __restrict__ dist,
                       float* __restrict__ gsum, float* __restrict__ gsq) {
  int e = blockIdx.x * 256 + threadIdx.x;
  int s = src[e], t = dst[e];
  float dx = pos[3 * s]     - pos[3 * t];
  float dy = pos[3 * s + 1] - pos[3 * t + 1];
  float dz = pos[3 * s + 2] - pos[3 * t + 2];
  float d = sqrtf(dx * dx + dy * dy + dz * dz);
  dist[e] = d;
  float s1 = d, s2 = d * d;
  for (int o = 32; o; o >>= 1) { s1 += __shfl_down(s1, o); s2 += __shfl_down(s2, o); }
  __shared__ float r1[4], r2[4];
  int w = threadIdx.x >> 6;
  if ((threadIdx.x & 63) == 0) { r1[w] = s1; r2[w] = s2; }
  __syncthreads();
  if (threadIdx.x == 0) {
    int g = e >> 14;
    atomicAdd(&gsum[g], r1[0] + r1[1] + r1[2] + r1[3]);
    atomicAdd(&gsq[g],  r2[0] + r2[1] + r2[2] + r2[3]);
  }
}

__global__ void k_efin(const float* __restrict__ gsum, const float* __restrict__ gsq,
                       const float* __restrict__ dnw, const float* __restrict__ dnb,
                       const float* __restrict__ dnms, float* __restrict__ ga, float* __restrict__ gb) {
  int g = threadIdx.x;
  if (g < NG) {
    float ms = dnms[0];
    float mean = gsum[g] * (1.f / EPG);
    float var = gsq[g] * (1.f / EPG) - (2.f * ms - ms * ms) * mean * mean;
    float a = dnw[0] * rsqrtf(var + 1e-5f);
    ga[g] = a;
    gb[g] = dnb[0] - a * ms * mean;
  }
}

__global__ void k_embed(const float4* __restrict__ emb, const int* __restrict__ at,
                        float4* __restrict__ h) {
  int gid = blockIdx.x * 256 + threadIdx.x;
  int i = gid >> 5, q = gid & 31;
  h[gid] = emb[at[i] * 32 + q];
}

// =============== per-layer edge MoE router ===============
__global__ void k_edge(const float* __restrict__ dist,
                       const float* __restrict__ ga, const float* __restrict__ gb,
                       const float* __restrict__ ew1, const float* __restrict__ eb1,
                       const float* __restrict__ ew2, const float* __restrict__ eb2,
                       float* __restrict__ eaw, float* __restrict__ part) {
  __shared__ float w1s[EHID], b1s[EHID];
  __shared__ __align__(16) float w2s[EHID * NEXPT];
  __shared__ float b2s[NEXPT];
  int t = threadIdx.x;
  if (t < EHID) { w1s[t] = ew1[t]; b1s[t] = eb1[t]; }
  if (t < NEXPT) b2s[t] = eb2[t];
  for (int j = t; j < EHID * NEXPT; j += 256) w2s[j] = ew2[j];
  __syncthreads();

  int e0 = blockIdx.x * 1024 + t * 4;
  float4 dv = *(const float4*)&dist[e0];
  float dd[4] = {dv.x, dv.y, dv.z, dv.w};
  int g = e0 >> 14;
  float gav = ga[g], gbv = gb[g];
  float a0[4], ewv[4];
#pragma unroll
  for (int j = 0; j < 4; ++j) {
    a0[j] = gav * dd[j] + gbv;
    ewv[j] = (10.0f - dd[j]) * 0.1f;
  }
  float acc[4][NEXPT];
#pragma unroll
  for (int j = 0; j < 4; ++j)
#pragma unroll
    for (int x = 0; x < NEXPT; ++x) acc[j][x] = b2s[x];

  for (int k = 0; k < EHID; ++k) {
    float w1k = w1s[k], b1k = b1s[k];
    float hk[4];
#pragma unroll
    for (int j = 0; j < 4; ++j) hk[j] = fmaxf(a0[j] * w1k + b1k, 0.f);
    float4 wa = *(const float4*)&w2s[k * 8];
    float4 wb = *(const float4*)&w2s[k * 8 + 4];
    float ww[8] = {wa.x, wa.y, wa.z, wa.w, wb.x, wb.y, wb.z, wb.w};
#pragma unroll
    for (int j = 0; j < 4; ++j)
#pragma unroll
      for (int x = 0; x < NEXPT; ++x) acc[j][x] += hk[j] * ww[x];
  }

  float esum[NEXPT] = {0, 0, 0, 0, 0, 0, 0, 0};
#pragma unroll
  for (int j = 0; j < 4; ++j) {
    float m = acc[j][0];
#pragma unroll
    for (int x = 1; x < NEXPT; ++x) m = fmaxf(m, acc[j][x]);
    float p[NEXPT], s = 0.f;
#pragma unroll
    for (int x = 0; x < NEXPT; ++x) { p[x] = __expf(acc[j][x] - m); s += p[x]; }
    float inv = 1.f / s;
    float fw = ewv[j] * inv;
    float4 o0 = {p[0] * fw, p[1] * fw, p[2] * fw, p[3] * fw};
    float4 o1 = {p[4] * fw, p[5] * fw, p[6] * fw, p[7] * fw};
    *(float4*)&eaw[(size_t)(e0 + j) * 8]     = o0;
    *(float4*)&eaw[(size_t)(e0 + j) * 8 + 4] = o1;
#pragma unroll
    for (int x = 0; x < NEXPT; ++x) esum[x] += p[x] * inv;
  }
  for (int o = 32; o; o >>= 1)
#pragma unroll
    for (int x = 0; x < NEXPT; ++x) esum[x] += __shfl_down(esum[x], o);
  __shared__ float ps[4][NEXPT];
  int w = t >> 6;
  if ((t & 63) == 0)
#pragma unroll
    for (int x = 0; x < NEXPT; ++x) ps[w][x] = esum[x];
  __syncthreads();
  if (t < NEXPT) part[blockIdx.x * NEXPT + t] = ps[0][t] + ps[1][t] + ps[2][t] + ps[3][t];
}

// =============== aggregation -> bf16 agg[x][i][k] ===============
// grid NN/8, block 256: 32-thread slice per node (lane = 4-dim chunk).
__global__ __launch_bounds__(256) void k_agg(const float* __restrict__ h, const int* __restrict__ src,
                      const float* __restrict__ eaw, unsigned short* __restrict__ agg) {
  const int t = threadIdx.x;
  const int s = t >> 5;       // node slice 0..7
  const int lane = t & 31;    // dim chunk (4 floats)
  const int i = blockIdx.x * 8 + s;
  __shared__ int ssrc[8][DEG];
  __shared__ __align__(16) float sw[8][DEG][NEXPT];  // [slice][edge][expert]
  const int e0b = blockIdx.x * 8 * DEG;
  ssrc[s][lane] = src[e0b + t];
  {
    const float4* ep = (const float4*)&eaw[(size_t)e0b * 8];  // 512 float4
    float4* sp = (float4*)&sw[0][0][0];
    sp[t] = ep[t];
    sp[t + 256] = ep[t + 256];
  }
  __syncthreads();
  f4 acc[NEXPT];
#pragma unroll
  for (int x = 0; x < NEXPT; ++x) acc[x] = (f4)0.f;
#pragma unroll 2
  for (int k = 0; k < DEG; ++k) {
    f4 hv = *(const f4*)&h[(size_t)ssrc[s][k] * 128 + lane * 4];
    f4 w0 = *(const f4*)&sw[s][k][0];   // broadcast within slice
    f4 w1 = *(const f4*)&sw[s][k][4];
    float ww[8] = {w0[0], w0[1], w0[2], w0[3], w1[0], w1[1], w1[2], w1[3]};
#pragma unroll
    for (int x = 0; x < NEXPT; ++x) acc[x] += ww[x] * hv;
  }
#pragma unroll
  for (int x = 0; x < NEXPT; ++x) {
    uint2 pk;
    pk.x = bf16pair(acc[x][0], acc[x][1]);
    pk.y = bf16pair(acc[x][2], acc[x][3]);
    *(uint2*)&agg[((size_t)x * NN + i) * 128 + lane * 4] = pk;
  }
}

// =============== MFMA expert MLP ===============
// 64-node tile, 512 threads (8 waves) -> grid 256 = 1 block/CU, 8 waves/CU.
// Per-block weight traffic is fixed (~1MB: all experts), so 256 blocks is the
// traffic-minimal grid; 8 waves give the latency hiding round 6 lacked.
// hid double-buffered (2x32KB) -> ONE barrier per expert (the prior reader of
// buffer x&1 finished before the preceding collective barrier).
//   GEMM1: D1[h][n] = W1T(256x128) x aggT(128x64); wave w: h in [32w,32w+32)
//   GEMM2: D2[d][n] = W2T(128x256) x hidT(256x64); wave w: d in [16w,16w+16)
// mfma_f32_16x16x32_bf16 mapping (m89): A[m=l&15][k=(l>>4)*8+j], B[k][n=l&15], D[m=(l>>4)*4+r][n=l&15]
__global__ __launch_bounds__(512) void k_mlp(
    const unsigned short* __restrict__ agg,  // [8][NN][128] bf16
    const unsigned short* __restrict__ w1t,  // [8][256][128] bf16  (h-major, k contig)
    const float* __restrict__ b1g,           // [8][256]
    const unsigned short* __restrict__ w2t,  // [8][128][256] bf16  (d-major, h contig)
    const float* __restrict__ b2g,           // [8][128]
    float* __restrict__ out) {               // [NN][128]
  __shared__ unsigned short hid[2][64 * 256];  // [buf][node][h] bf16, byte ^= (node&7)<<4
  char* hb = (char*)hid;
  const int t = threadIdx.x;
  const int w = t >> 6;         // wave 0..7
  const int l15 = t & 15;
  const int q = (t & 63) >> 4;  // 0..3
  const int i0 = blockIdx.x * 64;

  f4 acc2[4];
#pragma unroll
  for (int nt = 0; nt < 4; ++nt) acc2[nt] = (f4)0.f;

  for (int x = 0; x < NEXPT; ++x) {
    const int bufb = (x & 1) * 32768;  // byte offset of current hid buffer
    // ---- GEMM1: wave w covers h in [32w, 32w+32) ----
    f4 acc1[2][4];
#pragma unroll
    for (int ht = 0; ht < 2; ++ht) {
      f4 bb = *(const f4*)&b1g[x * 256 + 32 * w + 16 * ht + 4 * q];
#pragma unroll
      for (int nt = 0; nt < 4; ++nt) acc1[ht][nt] = bb;
    }
#pragma unroll
    for (int ks = 0; ks < 4; ++ks) {
      bh8 afr[2], bfr[4];
#pragma unroll
      for (int ht = 0; ht < 2; ++ht)
        afr[ht] = *(const bh8*)&w1t[((size_t)x * 256 + 32 * w + 16 * ht + l15) * 128 + ks * 32 + q * 8];
#pragma unroll
      for (int nt = 0; nt < 4; ++nt)
        bfr[nt] = *(const bh8*)&agg[((size_t)x * NN + i0 + 16 * nt + l15) * 128 + ks * 32 + q * 8];
#pragma unroll
      for (int ht = 0; ht < 2; ++ht)
#pragma unroll
        for (int nt = 0; nt < 4; ++nt)
          acc1[ht][nt] = __builtin_amdgcn_mfma_f32_16x16x32_bf16(afr[ht], bfr[nt], acc1[ht][nt], 0, 0, 0);
    }
    // relu + pack 2x bf16 -> swizzled LDS buffer (x&1)
#pragma unroll
    for (int ht = 0; ht < 2; ++ht)
#pragma unroll
      for (int nt = 0; nt < 4; ++nt) {
        int node = 16 * nt + l15;
        int h0 = 32 * w + 16 * ht + 4 * q;
        int byte0 = bufb + ((node * 512 + h0 * 2) ^ ((node & 7) << 4));
        *(unsigned int*)(hb + byte0) =
            bf16pair(fmaxf(acc1[ht][nt][0], 0.f), fmaxf(acc1[ht][nt][1], 0.f));
        *(unsigned int*)(hb + byte0 + 4) =
            bf16pair(fmaxf(acc1[ht][nt][2], 0.f), fmaxf(acc1[ht][nt][3], 0.f));
      }
    __syncthreads();  // hid[x&1] ready for all waves
    // ---- GEMM2: wave w covers d in [16w, 16w+16) ----
#pragma unroll
    for (int ks = 0; ks < 8; ++ks) {
      bh8 a2, b2f[4];
      a2 = *(const bh8*)&w2t[((size_t)x * 128 + 16 * w + l15) * 256 + ks * 32 + q * 8];
#pragma unroll
      for (int nt = 0; nt < 4; ++nt) {
        int node = 16 * nt + l15;
        int byte0 = bufb + ((node * 512 + ks * 64 + q * 16) ^ ((node & 7) << 4));
        b2f[nt] = *(const bh8*)(hb + byte0);
      }
#pragma unroll
      for (int nt = 0; nt < 4; ++nt)
        acc2[nt] = __builtin_amdgcn_mfma_f32_16x16x32_bf16(a2, b2f[nt], acc2[nt], 0, 0, 0);
    }
    // + b2 (per expert)
    {
      f4 bb = *(const f4*)&b2g[x * 128 + 16 * w + 4 * q];
#pragma unroll
      for (int nt = 0; nt < 4; ++nt) acc2[nt] += bb;
    }
  }
  // store: lane holds d = 16w+4q+r (contiguous 4), node = 16nt+l15
#pragma unroll
  for (int nt = 0; nt < 4; ++nt)
    *(f4*)&out[(size_t)(i0 + 16 * nt + l15) * 128 + 16 * w + 4 * q] = acc2[nt];
}

// =============== node GraphNorm ===============
__global__ void k_gnr(const float* __restrict__ h, float* __restrict__ nsum, float* __restrict__ nsq) {
  int g = blockIdx.x, strip = blockIdx.y;
  int c = threadIdx.x;
  const float* base = h + ((size_t)g * NPG + strip * 64) * 128 + c;
  float s = 0.f, q = 0.f;
  for (int n = 0; n < 64; ++n) { float v = base[(size_t)n * 128]; s += v; q += v * v; }
  atomicAdd(&nsum[g * 128 + c], s);
  atomicAdd(&nsq[g * 128 + c], q);
}

__global__ void k_gnf(const float* __restrict__ nsum, const float* __restrict__ nsq,
                      const float* __restrict__ gw, const float* __restrict__ gbv,
                      const float* __restrict__ gms, float* __restrict__ amul, float* __restrict__ aadd) {
  int idx = blockIdx.x * 256 + threadIdx.x;
  int c = idx & 127;
  float ms = gms[c];
  float mean = nsum[idx] * (1.f / NPG);
  float var = nsq[idx] * (1.f / NPG) - (2.f * ms - ms * ms) * mean * mean;
  float a = gw[c] * rsqrtf(var + 1e-5f);
  amul[idx] = a;
  aadd[idx] = gbv[c] - a * ms * mean;
}

__global__ void k_gna(float* __restrict__ h, const float* __restrict__ amul,
                      const float* __restrict__ aadd) {
  int gid = blockIdx.x * 256 + threadIdx.x;
  int i = gid >> 5, q = gid & 31;
  int g = i >> 9;
  float4 v = *(float4*)&h[(size_t)gid * 4];
  float4 a = *(const float4*)&amul[g * 128 + q * 4];
  float4 b = *(const float4*)&aadd[g * 128 + q * 4];
  v.x = tanhf(a.x * v.x + b.x);
  v.y = tanhf(a.y * v.y + b.y);
  v.z = tanhf(a.z * v.z + b.z);
  v.w = tanhf(a.w * v.w + b.w);
  *(float4*)&h[(size_t)gid * 4] = v;
}

// =============== final pooling + routing loss ===============
__global__ void k_pool(const float* __restrict__ h, float* __restrict__ outp) {
  int g = blockIdx.x, t = threadIdx.x;
  const float4* base = (const float4*)(h + (size_t)g * NPG * 128);
  float s = 0.f;
  for (int p = 0; p < 64; ++p) { float4 v = base[p * 256 + t]; s += v.x + v.y + v.z + v.w; }
  for (int o = 32; o; o >>= 1) s += __shfl_down(s, o);
  __shared__ float r[4];
  if ((t & 63) == 0) r[t >> 6] = s;
  __syncthreads();
  if (t == 0) outp[g] = (r[0] + r[1] + r[2] + r[3]) * (1.f / (NPG * 128));
}

__global__ void k_lbl(const float* __restrict__ part, float* __restrict__ outp) {
  __shared__ float s[NL * NEXPT];
  int t = threadIdx.x;
  if (t < NL * NEXPT) {
    int l = t >> 3, x = t & 7;
    float acc = 0.f;
    for (int b = 0; b < 512; ++b) acc += part[(size_t)(l * 512 + b) * NEXPT + x];
    s[t] = acc;
  }
  __syncthreads();
  if (t == 0) {
    float lbl = 0.f;
    for (int j = 0; j < NL * NEXPT; ++j) { float m = s[j] * (1.f / NE); lbl += m * m; }
    outp[0] = lbl * ((float)NEXPT / NL) * 0.1f;
  }
}

// =============== launcher ===============
extern "C" void kernel_launch(void* const* d_in, const int* in_sizes, int n_in,
                              void* d_out, int out_size, void* d_ws, size_t ws_size,
                              hipStream_t stream) {
  (void)in_sizes; (void)n_in; (void)out_size; (void)ws_size;
  const float* pos  = (const float*)d_in[0];
  const float* emb  = (const float*)d_in[1];
  const float* ew1  = (const float*)d_in[2];
  const float* eb1  = (const float*)d_in[3];
  const float* ew2  = (const float*)d_in[4];
  const float* eb2  = (const float*)d_in[5];
  const float* nw1  = (const float*)d_in[6];
  const float* nb1  = (const float*)d_in[7];
  const float* nw2  = (const float*)d_in[8];
  const float* nb2  = (const float*)d_in[9];
  const float* gnw  = (const float*)d_in[10];
  const float* gnb  = (const float*)d_in[11];
  const float* gnms = (const float*)d_in[12];
  const float* dnw  = (const float*)d_in[13];
  const float* dnb  = (const float*)d_in[14];
  const float* dnms = (const float*)d_in[15];
  const int* atom   = (const int*)d_in[16];
  const int* eidx   = (const int*)d_in[17];
  float* out = (float*)d_out;

  char* wsb = (char*)d_ws;
  float* dist = (float*)wsb;                 wsb += sizeof(float) * NE;
  float* eaw  = (float*)wsb;                 wsb += sizeof(float) * (size_t)NE * 8;
  unsigned short* aggb = (unsigned short*)wsb; wsb += sizeof(short) * (size_t)8 * NN * 128;
  unsigned short* w1t  = (unsigned short*)wsb; wsb += sizeof(short) * (size_t)NL * 8 * 256 * 128;
  unsigned short* w2t  = (unsigned short*)wsb; wsb += sizeof(short) * (size_t)NL * 8 * 256 * 128;
  float* hA   = (float*)wsb;                 wsb += sizeof(float) * (size_t)NN * 128;
  float* hB   = (float*)wsb;                 wsb += sizeof(float) * (size_t)NN * 128;
  float* gsum = (float*)wsb;                 wsb += sizeof(float) * NG;
  float* gsq  = (float*)wsb;                 wsb += sizeof(float) * NG;
  float* ga   = (float*)wsb;                 wsb += sizeof(float) * NG;
  float* gb   = (float*)wsb;                 wsb += sizeof(float) * NG;
  float* nsum = (float*)wsb;                 wsb += sizeof(float) * NG * 128;
  float* nsq  = (float*)wsb;                 wsb += sizeof(float) * NG * 128;
  float* amul = (float*)wsb;                 wsb += sizeof(float) * NG * 128;
  float* aadd = (float*)wsb;                 wsb += sizeof(float) * NG * 128;
  float* part = (float*)wsb;                 wsb += sizeof(float) * (size_t)NL * 512 * NEXPT;

  const int* srcA = eidx;
  const int* dstA = eidx + NE;

  k_zero<<<1, 256, 0, stream>>>((float4*)gsum, 16);  // gsum+gsq
  // pre-transpose weights to bf16: w1t[l,x][h][k], w2t[l,x][d][h]
  {
    dim3 g1(HIDN / 32, DD / 32, NL * NEXPT);
    k_tr<<<g1, 256, 0, stream>>>(nw1, w1t, DD, HIDN);
    dim3 g2(DD / 32, HIDN / 32, NL * NEXPT);
    k_tr<<<g2, 256, 0, stream>>>(nw2, w2t, HIDN, DD);
  }
  k_dist<<<NE / 256, 256, 0, stream>>>(pos, srcA, dstA, dist, gsum, gsq);
  k_efin<<<1, 64, 0, stream>>>(gsum, gsq, dnw, dnb, dnms, ga, gb);
  k_embed<<<NN * 32 / 256, 256, 0, stream>>>((const float4*)emb, atom, (float4*)hA);

  float* hcur = hA;
  float* hnxt = hB;
  for (int l = 0; l < NL; ++l) {
    k_edge<<<NE / 1024, 256, 0, stream>>>(dist, ga, gb, ew1 + l * EHID, eb1 + l * EHID,
                                          ew2 + (size_t)l * EHID * NEXPT, eb2 + l * NEXPT,
                                          eaw, part + (size_t)l * 512 * NEXPT);
    k_agg<<<NN / 8, 256, 0, stream>>>(hcur, srcA, eaw, aggb);
    k_mlp<<<NN / 64, 512, 0, stream>>>(aggb,
                                       w1t + (size_t)l * 8 * 256 * 128,
                                       nb1 + (size_t)l * 8 * 256,
                                       w2t + (size_t)l * 8 * 256 * 128,
                                       nb2 + (size_t)l * 8 * 128, hnxt);
    if (l + 1 < NL) {
      k_zero<<<8, 256, 0, stream>>>((float4*)nsum, 2048);  // nsum+nsq
      dim3 gr(NG, 8);
      k_gnr<<<gr, 128, 0, stream>>>(hnxt, nsum, nsq);
      k_gnf<<<16, 256, 0, stream>>>(nsum, nsq, gnw + l * 128, gnb + l * 128, gnms + l * 128,
                                    amul, aadd);
      k_gna<<<NN * 32 / 256, 256, 0, stream>>>(hnxt, amul, aadd);
    }
    float* tmp = hcur; hcur = hnxt; hnxt = tmp;
  }
  k_pool<<<NG, 256, 0, stream>>>(hcur, out);
  k_lbl<<<1, 64, 0, stream>>>(part, out + NG);
}

// Round 10
// 492.740 us; speedup vs baseline: 1.0917x; 1.0327x over previous
//
#include <hip/hip_runtime.h>
#include <math.h>

// ---- problem constants (structural, from setup_inputs) ----
#define NG    32          // graphs
#define NPG   512         // nodes per graph
#define NN    16384       // N
#define DEG   32          // edges per node (dst-sorted: node i owns edges [32i,32i+32))
#define NE    524288      // E
#define EPG   16384       // edges per graph
#define DD    128
#define HIDN  256
#define NEXPT 8
#define EHID  64
#define NL    3

typedef __attribute__((ext_vector_type(8))) short bh8;   // 8 bf16 = 4 VGPRs (MFMA A/B frag)
typedef __attribute__((ext_vector_type(4))) float f4;    // MFMA C/D frag

// round-to-nearest-even f32 -> bf16
__device__ __forceinline__ unsigned short bf16_1(float x) {
  unsigned int u = __float_as_uint(x);
  return (unsigned short)((u + 0x7fffu + ((u >> 16) & 1u)) >> 16);
}
__device__ __forceinline__ unsigned int bf16pair(float a, float b) {
  return (unsigned int)bf16_1(a) | ((unsigned int)bf16_1(b) << 16);
}

// =============== utility ===============
__global__ void k_zero(float4* p, int n4) {
  int i = blockIdx.x * 256 + threadIdx.x;
  if (i < n4) p[i] = make_float4(0.f, 0.f, 0.f, 0.f);
}

// transpose one [M][N] f32 matrix per blockIdx.z -> [N][M] bf16
__global__ void k_tr(const float* __restrict__ in, unsigned short* __restrict__ outp,
                     int M, int N) {
  __shared__ float tile[32][33];
  const float* ip = in + (size_t)blockIdx.z * M * N;
  unsigned short* op = outp + (size_t)blockIdx.z * M * N;
  int t = threadIdx.x;
  int i = t >> 5, j = t & 31;
  int c0 = blockIdx.x * 32, r0 = blockIdx.y * 32;
#pragma unroll
  for (int p = 0; p < 4; ++p)
    tile[i + 8 * p][j] = ip[(size_t)(r0 + i + 8 * p) * N + c0 + j];
  __syncthreads();
#pragma unroll
  for (int p = 0; p < 4; ++p)
    op[(size_t)(c0 + i + 8 * p) * M + r0 + j] = bf16_1(tile[j][i + 8 * p]);
}

// =============== dist + per-graph sum / sumsq ===============
__global__ void k_dist(const float* __restrict__ pos, const int* __restrict__ src,
                       const int* __restrict__ dst, float* __restrict__ dist,
                       float* __restrict__ gsum, float* __restrict__ gsq) {
  int e = blockIdx.x * 256 + threadIdx.x;
  int s = src[e], t = dst[e];
  float dx = pos[3 * s]     - pos[3 * t];
  float dy = pos[3 * s + 1] - pos[3 * t + 1];
  float dz = pos[3 * s + 2] - pos[3 * t + 2];
  float d = sqrtf(dx * dx + dy * dy + dz * dz);
  dist[e] = d;
  float s1 = d, s2 = d * d;
  for (int o = 32; o; o >>= 1) { s1 += __shfl_down(s1, o); s2 += __shfl_down(s2, o); }
  __shared__ float r1[4], r2[4];
  int w = threadIdx.x >> 6;
  if ((threadIdx.x & 63) == 0) { r1[w] = s1; r2[w] = s2; }
  __syncthreads();
  if (threadIdx.x == 0) {
    int g = e >> 14;
    atomicAdd(&gsum[g], r1[0] + r1[1] + r1[2] + r1[3]);
    atomicAdd(&gsq[g],  r2[0] + r2[1] + r2[2] + r2[3]);
  }
}

__global__ void k_efin(const float* __restrict__ gsum, const float* __restrict__ gsq,
                       const float* __restrict__ dnw, const float* __restrict__ dnb,
                       const float* __restrict__ dnms, float* __restrict__ ga, float* __restrict__ gb) {
  int g = threadIdx.x;
  if (g < NG) {
    float ms = dnms[0];
    float mean = gsum[g] * (1.f / EPG);
    float var = gsq[g] * (1.f / EPG) - (2.f * ms - ms * ms) * mean * mean;
    float a = dnw[0] * rsqrtf(var + 1e-5f);
    ga[g] = a;
    gb[g] = dnb[0] - a * ms * mean;
  }
}

__global__ void k_embed(const float4* __restrict__ emb, const int* __restrict__ at,
                        float4* __restrict__ h) {
  int gid = blockIdx.x * 256 + threadIdx.x;
  int i = gid >> 5, q = gid & 31;
  h[gid] = emb[at[i] * 32 + q];
}

// =============== per-layer edge MoE router ===============
__global__ void k_edge(const float* __restrict__ dist,
                       const float* __restrict__ ga, const float* __restrict__ gb,
                       const float* __restrict__ ew1, const float* __restrict__ eb1,
                       const float* __restrict__ ew2, const float* __restrict__ eb2,
                       float* __restrict__ eaw, float* __restrict__ part) {
  __shared__ float w1s[EHID], b1s[EHID];
  __shared__ __align__(16) float w2s[EHID * NEXPT];
  __shared__ float b2s[NEXPT];
  int t = threadIdx.x;
  if (t < EHID) { w1s[t] = ew1[t]; b1s[t] = eb1[t]; }
  if (t < NEXPT) b2s[t] = eb2[t];
  for (int j = t; j < EHID * NEXPT; j += 256) w2s[j] = ew2[j];
  __syncthreads();

  int e0 = blockIdx.x * 1024 + t * 4;
  float4 dv = *(const float4*)&dist[e0];
  float dd[4] = {dv.x, dv.y, dv.z, dv.w};
  int g = e0 >> 14;
  float gav = ga[g], gbv = gb[g];
  float a0[4], ewv[4];
#pragma unroll
  for (int j = 0; j < 4; ++j) {
    a0[j] = gav * dd[j] + gbv;
    ewv[j] = (10.0f - dd[j]) * 0.1f;
  }
  float acc[4][NEXPT];
#pragma unroll
  for (int j = 0; j < 4; ++j)
#pragma unroll
    for (int x = 0; x < NEXPT; ++x) acc[j][x] = b2s[x];

  for (int k = 0; k < EHID; ++k) {
    float w1k = w1s[k], b1k = b1s[k];
    float hk[4];
#pragma unroll
    for (int j = 0; j < 4; ++j) hk[j] = fmaxf(a0[j] * w1k + b1k, 0.f);
    float4 wa = *(const float4*)&w2s[k * 8];
    float4 wb = *(const float4*)&w2s[k * 8 + 4];
    float ww[8] = {wa.x, wa.y, wa.z, wa.w, wb.x, wb.y, wb.z, wb.w};
#pragma unroll
    for (int j = 0; j < 4; ++j)
#pragma unroll
      for (int x = 0; x < NEXPT; ++x) acc[j][x] += hk[j] * ww[x];
  }

  float esum[NEXPT] = {0, 0, 0, 0, 0, 0, 0, 0};
#pragma unroll
  for (int j = 0; j < 4; ++j) {
    float m = acc[j][0];
#pragma unroll
    for (int x = 1; x < NEXPT; ++x) m = fmaxf(m, acc[j][x]);
    float p[NEXPT], s = 0.f;
#pragma unroll
    for (int x = 0; x < NEXPT; ++x) { p[x] = __expf(acc[j][x] - m); s += p[x]; }
    float inv = 1.f / s;
    float fw = ewv[j] * inv;
    float4 o0 = {p[0] * fw, p[1] * fw, p[2] * fw, p[3] * fw};
    float4 o1 = {p[4] * fw, p[5] * fw, p[6] * fw, p[7] * fw};
    *(float4*)&eaw[(size_t)(e0 + j) * 8]     = o0;
    *(float4*)&eaw[(size_t)(e0 + j) * 8 + 4] = o1;
#pragma unroll
    for (int x = 0; x < NEXPT; ++x) esum[x] += p[x] * inv;
  }
  for (int o = 32; o; o >>= 1)
#pragma unroll
    for (int x = 0; x < NEXPT; ++x) esum[x] += __shfl_down(esum[x], o);
  __shared__ float ps[4][NEXPT];
  int w = t >> 6;
  if ((t & 63) == 0)
#pragma unroll
    for (int x = 0; x < NEXPT; ++x) ps[w][x] = esum[x];
  __syncthreads();
  if (t < NEXPT) part[blockIdx.x * NEXPT + t] = ps[0][t] + ps[1][t] + ps[2][t] + ps[3][t];
}

// =============== aggregation -> bf16 agg[x][i][k] ===============
// grid NN/8, block 256: 32-thread slice per node (lane = 4-dim chunk).
__global__ __launch_bounds__(256) void k_agg(const float* __restrict__ h, const int* __restrict__ src,
                      const float* __restrict__ eaw, unsigned short* __restrict__ agg) {
  const int t = threadIdx.x;
  const int s = t >> 5;       // node slice 0..7
  const int lane = t & 31;    // dim chunk (4 floats)
  const int i = blockIdx.x * 8 + s;
  __shared__ int ssrc[8][DEG];
  __shared__ __align__(16) float sw[8][DEG][NEXPT];  // [slice][edge][expert]
  const int e0b = blockIdx.x * 8 * DEG;
  ssrc[s][lane] = src[e0b + t];
  {
    const float4* ep = (const float4*)&eaw[(size_t)e0b * 8];  // 512 float4
    float4* sp = (float4*)&sw[0][0][0];
    sp[t] = ep[t];
    sp[t + 256] = ep[t + 256];
  }
  __syncthreads();
  f4 acc[NEXPT];
#pragma unroll
  for (int x = 0; x < NEXPT; ++x) acc[x] = (f4)0.f;
#pragma unroll 2
  for (int k = 0; k < DEG; ++k) {
    f4 hv = *(const f4*)&h[(size_t)ssrc[s][k] * 128 + lane * 4];
    f4 w0 = *(const f4*)&sw[s][k][0];   // broadcast within slice
    f4 w1 = *(const f4*)&sw[s][k][4];
    float ww[8] = {w0[0], w0[1], w0[2], w0[3], w1[0], w1[1], w1[2], w1[3]};
#pragma unroll
    for (int x = 0; x < NEXPT; ++x) acc[x] += ww[x] * hv;
  }
#pragma unroll
  for (int x = 0; x < NEXPT; ++x) {
    uint2 pk;
    pk.x = bf16pair(acc[x][0], acc[x][1]);
    pk.y = bf16pair(acc[x][2], acc[x][3]);
    *(uint2*)&agg[((size_t)x * NN + i) * 128 + lane * 4] = pk;
  }
}

// =============== MFMA expert MLP (split expert groups across blocks) ===============
// grid (NN/64, 2), block 256 (4 waves). blockIdx.y = expert group (4 experts each)
// -> 2 INDEPENDENT blocks per CU: separate barrier domains, so one block's waves
// cover the other's vmcnt(0) barrier drains. Weight L2 traffic unchanged vs the
// 8-expert loop (it depends only on the 64-node tile count, not the split).
// hid double-buffered (2x32KB) -> ONE barrier per expert (reads of buf b in
// GEMM2(x-1) all precede bar(x); writes to buf b in GEMM1(x+1) all follow it).
// Partial (no b2) written non-atomically to part[xg][NN][128]; k_red sums.
// mfma_f32_16x16x32_bf16 mapping (m89): A[m=l&15][k=(l>>4)*8+j], B[k][n=l&15], D[m=(l>>4)*4+r][n=l&15]
__global__ __launch_bounds__(256) void k_mlp(
    const unsigned short* __restrict__ agg,  // [8][NN][128] bf16
    const unsigned short* __restrict__ w1t,  // [8][256][128] bf16  (h-major, k contig)
    const float* __restrict__ b1g,           // [8][256]
    const unsigned short* __restrict__ w2t,  // [8][128][256] bf16  (d-major, h contig)
    float* __restrict__ part) {              // [2][NN][128] f32 partials
  __shared__ unsigned short hid[2][64 * 256];  // [buf][node][h] bf16, byte ^= (node&7)<<4
  char* hb = (char*)hid;
  const int t = threadIdx.x;
  const int w = t >> 6;         // wave 0..3
  const int l15 = t & 15;
  const int q = (t & 63) >> 4;  // 0..3
  const int i0 = blockIdx.x * 64;
  const int x0 = blockIdx.y * 4;  // expert group base
  float* pout = part + (size_t)blockIdx.y * NN * 128;

  f4 acc2[2][4];
#pragma unroll
  for (int dt = 0; dt < 2; ++dt)
#pragma unroll
    for (int nt = 0; nt < 4; ++nt) acc2[dt][nt] = (f4)0.f;

  for (int xi = 0; xi < 4; ++xi) {
    const int x = x0 + xi;
    const int bufb = (xi & 1) * 32768;  // byte offset of current hid buffer
    // ---- GEMM1: wave w covers h in [64w, 64w+64) ----
    f4 acc1[4][4];
#pragma unroll
    for (int ht = 0; ht < 4; ++ht) {
      f4 bb = *(const f4*)&b1g[x * 256 + 64 * w + 16 * ht + 4 * q];
#pragma unroll
      for (int nt = 0; nt < 4; ++nt) acc1[ht][nt] = bb;
    }
#pragma unroll
    for (int ks = 0; ks < 4; ++ks) {
      bh8 afr[4], bfr[4];
#pragma unroll
      for (int ht = 0; ht < 4; ++ht)
        afr[ht] = *(const bh8*)&w1t[((size_t)x * 256 + 64 * w + 16 * ht + l15) * 128 + ks * 32 + q * 8];
#pragma unroll
      for (int nt = 0; nt < 4; ++nt)
        bfr[nt] = *(const bh8*)&agg[((size_t)x * NN + i0 + 16 * nt + l15) * 128 + ks * 32 + q * 8];
#pragma unroll
      for (int ht = 0; ht < 4; ++ht)
#pragma unroll
        for (int nt = 0; nt < 4; ++nt)
          acc1[ht][nt] = __builtin_amdgcn_mfma_f32_16x16x32_bf16(afr[ht], bfr[nt], acc1[ht][nt], 0, 0, 0);
    }
    // relu + pack 2x bf16 -> swizzled LDS buffer (xi&1)
#pragma unroll
    for (int ht = 0; ht < 4; ++ht)
#pragma unroll
      for (int nt = 0; nt < 4; ++nt) {
        int node = 16 * nt + l15;
        int h0 = 64 * w + 16 * ht + 4 * q;
        int byte0 = bufb + ((node * 512 + h0 * 2) ^ ((node & 7) << 4));
        *(unsigned int*)(hb + byte0) =
            bf16pair(fmaxf(acc1[ht][nt][0], 0.f), fmaxf(acc1[ht][nt][1], 0.f));
        *(unsigned int*)(hb + byte0 + 4) =
            bf16pair(fmaxf(acc1[ht][nt][2], 0.f), fmaxf(acc1[ht][nt][3], 0.f));
      }
    __syncthreads();  // hid[xi&1] ready for all waves
    // ---- GEMM2: wave w covers d in [32w, 32w+32) ----
#pragma unroll
    for (int ks = 0; ks < 8; ++ks) {
      bh8 a2[2], b2f[4];
#pragma unroll
      for (int dt = 0; dt < 2; ++dt)
        a2[dt] = *(const bh8*)&w2t[((size_t)x * 128 + 32 * w + 16 * dt + l15) * 256 + ks * 32 + q * 8];
#pragma unroll
      for (int nt = 0; nt < 4; ++nt) {
        int node = 16 * nt + l15;
        int byte0 = bufb + ((node * 512 + ks * 64 + q * 16) ^ ((node & 7) << 4));
        b2f[nt] = *(const bh8*)(hb + byte0);
      }
#pragma unroll
      for (int dt = 0; dt < 2; ++dt)
#pragma unroll
        for (int nt = 0; nt < 4; ++nt)
          acc2[dt][nt] = __builtin_amdgcn_mfma_f32_16x16x32_bf16(a2[dt], b2f[nt], acc2[dt][nt], 0, 0, 0);
    }
  }
  // store partial: lane holds d = 32w+16dt+4q+r (contiguous 4), node = 16nt+l15
#pragma unroll
  for (int dt = 0; dt < 2; ++dt)
#pragma unroll
    for (int nt = 0; nt < 4; ++nt)
      *(f4*)&pout[(size_t)(i0 + 16 * nt + l15) * 128 + 32 * w + 16 * dt + 4 * q] = acc2[dt][nt];
}

// =============== reduce partials + b2 (summed over all 8 experts) ===============
// grid NN*128/4/256 = 2048, block 256. hnxt = part0 + part1 + sum_x b2[x]
__global__ void k_red(const float4* __restrict__ part, float4* __restrict__ outp,
                      const float* __restrict__ b2g) {
  int i = blockIdx.x * 256 + threadIdx.x;  // over NN*128/4 float4
  int d4 = i & 31;                          // float4 index within the 128-d row
  float4 b = make_float4(0.f, 0.f, 0.f, 0.f);
#pragma unroll
  for (int x = 0; x < NEXPT; ++x) {
    float4 bv = *(const float4*)&b2g[x * 128 + d4 * 4];
    b.x += bv.x; b.y += bv.y; b.z += bv.z; b.w += bv.w;
  }
  float4 a0 = part[i];
  float4 a1 = part[i + NN * 128 / 4];
  float4 r = {a0.x + a1.x + b.x, a0.y + a1.y + b.y, a0.z + a1.z + b.z, a0.w + a1.w + b.w};
  outp[i] = r;
}

// =============== node GraphNorm ===============
__global__ void k_gnr(const float* __restrict__ h, float* __restrict__ nsum, float* __restrict__ nsq) {
  int g = blockIdx.x, strip = blockIdx.y;
  int c = threadIdx.x;
  const float* base = h + ((size_t)g * NPG + strip * 64) * 128 + c;
  float s = 0.f, q = 0.f;
  for (int n = 0; n < 64; ++n) { float v = base[(size_t)n * 128]; s += v; q += v * v; }
  atomicAdd(&nsum[g * 128 + c], s);
  atomicAdd(&nsq[g * 128 + c], q);
}

__global__ void k_gnf(const float* __restrict__ nsum, const float* __restrict__ nsq,
                      const float* __restrict__ gw, const float* __restrict__ gbv,
                      const float* __restrict__ gms, float* __restrict__ amul, float* __restrict__ aadd) {
  int idx = blockIdx.x * 256 + threadIdx.x;
  int c = idx & 127;
  float ms = gms[c];
  float mean = nsum[idx] * (1.f / NPG);
  float var = nsq[idx] * (1.f / NPG) - (2.f * ms - ms * ms) * mean * mean;
  float a = gw[c] * rsqrtf(var + 1e-5f);
  amul[idx] = a;
  aadd[idx] = gbv[c] - a * ms * mean;
}

__global__ void k_gna(float* __restrict__ h, const float* __restrict__ amul,
                      const float* __restrict__ aadd) {
  int gid = blockIdx.x * 256 + threadIdx.x;
  int i = gid >> 5, q = gid & 31;
  int g = i >> 9;
  float4 v = *(float4*)&h[(size_t)gid * 4];
  float4 a = *(const float4*)&amul[g * 128 + q * 4];
  float4 b = *(const float4*)&aadd[g * 128 + q * 4];
  v.x = tanhf(a.x * v.x + b.x);
  v.y = tanhf(a.y * v.y + b.y);
  v.z = tanhf(a.z * v.z + b.z);
  v.w = tanhf(a.w * v.w + b.w);
  *(float4*)&h[(size_t)gid * 4] = v;
}

// =============== final pooling + routing loss ===============
__global__ void k_pool(const float* __restrict__ h, float* __restrict__ outp) {
  int g = blockIdx.x, t = threadIdx.x;
  const float4* base = (const float4*)(h + (size_t)g * NPG * 128);
  float s = 0.f;
  for (int p = 0; p < 64; ++p) { float4 v = base[p * 256 + t]; s += v.x + v.y + v.z + v.w; }
  for (int o = 32; o; o >>= 1) s += __shfl_down(s, o);
  __shared__ float r[4];
  if ((t & 63) == 0) r[t >> 6] = s;
  __syncthreads();
  if (t == 0) outp[g] = (r[0] + r[1] + r[2] + r[3]) * (1.f / (NPG * 128));
}

__global__ void k_lbl(const float* __restrict__ part, float* __restrict__ outp) {
  __shared__ float s[NL * NEXPT];
  int t = threadIdx.x;
  if (t < NL * NEXPT) {
    int l = t >> 3, x = t & 7;
    float acc = 0.f;
    for (int b = 0; b < 512; ++b) acc += part[(size_t)(l * 512 + b) * NEXPT + x];
    s[t] = acc;
  }
  __syncthreads();
  if (t == 0) {
    float lbl = 0.f;
    for (int j = 0; j < NL * NEXPT; ++j) { float m = s[j] * (1.f / NE); lbl += m * m; }
    outp[0] = lbl * ((float)NEXPT / NL) * 0.1f;
  }
}

// =============== launcher ===============
extern "C" void kernel_launch(void* const* d_in, const int* in_sizes, int n_in,
                              void* d_out, int out_size, void* d_ws, size_t ws_size,
                              hipStream_t stream) {
  (void)in_sizes; (void)n_in; (void)out_size; (void)ws_size;
  const float* pos  = (const float*)d_in[0];
  const float* emb  = (const float*)d_in[1];
  const float* ew1  = (const float*)d_in[2];
  const float* eb1  = (const float*)d_in[3];
  const float* ew2  = (const float*)d_in[4];
  const float* eb2  = (const float*)d_in[5];
  const float* nw1  = (const float*)d_in[6];
  const float* nb1  = (const float*)d_in[7];
  const float* nw2  = (const float*)d_in[8];
  const float* nb2  = (const float*)d_in[9];
  const float* gnw  = (const float*)d_in[10];
  const float* gnb  = (const float*)d_in[11];
  const float* gnms = (const float*)d_in[12];
  const float* dnw  = (const float*)d_in[13];
  const float* dnb  = (const float*)d_in[14];
  const float* dnms = (const float*)d_in[15];
  const int* atom   = (const int*)d_in[16];
  const int* eidx   = (const int*)d_in[17];
  float* out = (float*)d_out;

  char* wsb = (char*)d_ws;
  float* dist = (float*)wsb;                 wsb += sizeof(float) * NE;
  float* eaw  = (float*)wsb;                 wsb += sizeof(float) * (size_t)NE * 8;
  unsigned short* aggb = (unsigned short*)wsb; wsb += sizeof(short) * (size_t)8 * NN * 128;
  unsigned short* w1t  = (unsigned short*)wsb; wsb += sizeof(short) * (size_t)NL * 8 * 256 * 128;
  unsigned short* w2t  = (unsigned short*)wsb; wsb += sizeof(short) * (size_t)NL * 8 * 256 * 128;
  float* hA   = (float*)wsb;                 wsb += sizeof(float) * (size_t)NN * 128;
  float* hB   = (float*)wsb;                 wsb += sizeof(float) * (size_t)NN * 128;
  float* gsum = (float*)wsb;                 wsb += sizeof(float) * NG;
  float* gsq  = (float*)wsb;                 wsb += sizeof(float) * NG;
  float* ga   = (float*)wsb;                 wsb += sizeof(float) * NG;
  float* gb   = (float*)wsb;                 wsb += sizeof(float) * NG;
  float* nsum = (float*)wsb;                 wsb += sizeof(float) * NG * 128;
  float* nsq  = (float*)wsb;                 wsb += sizeof(float) * NG * 128;
  float* amul = (float*)wsb;                 wsb += sizeof(float) * NG * 128;
  float* aadd = (float*)wsb;                 wsb += sizeof(float) * NG * 128;
  float* part = (float*)wsb;                 wsb += sizeof(float) * (size_t)NL * 512 * NEXPT;

  // expert-MLP partials [2][NN][128] f32 alias onto eaw (16.78 MB each):
  // eaw is consumed by k_agg before k_mlp writes it, and rewritten by the
  // next layer's k_edge after k_red has consumed the partials.
  float* mpart = eaw;

  const int* srcA = eidx;
  const int* dstA = eidx + NE;

  k_zero<<<1, 256, 0, stream>>>((float4*)gsum, 16);  // gsum+gsq
  // pre-transpose weights to bf16: w1t[l,x][h][k], w2t[l,x][d][h]
  {
    dim3 g1(HIDN / 32, DD / 32, NL * NEXPT);
    k_tr<<<g1, 256, 0, stream>>>(nw1, w1t, DD, HIDN);
    dim3 g2(DD / 32, HIDN / 32, NL * NEXPT);
    k_tr<<<g2, 256, 0, stream>>>(nw2, w2t, HIDN, DD);
  }
  k_dist<<<NE / 256, 256, 0, stream>>>(pos, srcA, dstA, dist, gsum, gsq);
  k_efin<<<1, 64, 0, stream>>>(gsum, gsq, dnw, dnb, dnms, ga, gb);
  k_embed<<<NN * 32 / 256, 256, 0, stream>>>((const float4*)emb, atom, (float4*)hA);

  float* hcur = hA;
  float* hnxt = hB;
  for (int l = 0; l < NL; ++l) {
    k_edge<<<NE / 1024, 256, 0, stream>>>(dist, ga, gb, ew1 + l * EHID, eb1 + l * EHID,
                                          ew2 + (size_t)l * EHID * NEXPT, eb2 + l * NEXPT,
                                          eaw, part + (size_t)l * 512 * NEXPT);
    k_agg<<<NN / 8, 256, 0, stream>>>(hcur, srcA, eaw, aggb);
    {
      dim3 gm(NN / 64, 2);
      k_mlp<<<gm, 256, 0, stream>>>(aggb,
                                    w1t + (size_t)l * 8 * 256 * 128,
                                    nb1 + (size_t)l * 8 * 256,
                                    w2t + (size_t)l * 8 * 256 * 128,
                                    mpart);
    }
    k_red<<<NN * 128 / 4 / 256, 256, 0, stream>>>((const float4*)mpart, (float4*)hnxt,
                                                  nb2 + (size_t)l * 8 * 128);
    if (l + 1 < NL) {
      k_zero<<<8, 256, 0, stream>>>((float4*)nsum, 2048);  // nsum+nsq
      dim3 gr(NG, 8);
      k_gnr<<<gr, 128, 0, stream>>>(hnxt, nsum, nsq);
      k_gnf<<<16, 256, 0, stream>>>(nsum, nsq, gnw + l * 128, gnb + l * 128, gnms + l * 128,
                                    amul, aadd);
      k_gna<<<NN * 32 / 256, 256, 0, stream>>>(hnxt, amul, aadd);
    }
    float* tmp = hcur; hcur = hnxt; hnxt = tmp;
  }
  k_pool<<<NG, 256, 0, stream>>>(hcur, out);
  k_lbl<<<1, 64, 0, stream>>>(part, out + NG);
}

// Round 13
// 416.796 us; speedup vs baseline: 1.2906x; 1.1822x over previous
//
#include <hip/hip_runtime.h>
#include <math.h>

// ---- problem constants (structural, from setup_inputs) ----
#define NG    32          // graphs
#define NPG   512         // nodes per graph
#define NN    16384       // N
#define DEG   32          // edges per node (dst-sorted: node i owns edges [32i,32i+32))
#define NE    524288      // E
#define EPG   16384       // edges per graph
#define DD    128
#define HIDN  256
#define NEXPT 8
#define EHID  64
#define NL    3

typedef __attribute__((ext_vector_type(8))) short bh8;   // 8 bf16 = 4 VGPRs (MFMA A/B frag)
typedef __attribute__((ext_vector_type(4))) float f4;    // MFMA C/D frag

// round-to-nearest-even f32 -> bf16
__device__ __forceinline__ unsigned short bf16_1(float x) {
  unsigned int u = __float_as_uint(x);
  return (unsigned short)((u + 0x7fffu + ((u >> 16) & 1u)) >> 16);
}
__device__ __forceinline__ unsigned int bf16pair(float a, float b) {
  return (unsigned int)bf16_1(a) | ((unsigned int)bf16_1(b) << 16);
}

// =============== utility ===============
__global__ void k_zero(float4* p, int n4) {
  int i = blockIdx.x * 256 + threadIdx.x;
  if (i < n4) p[i] = make_float4(0.f, 0.f, 0.f, 0.f);
}

// =============== weight pre-swizzle into MFMA fragment order ===============
// w1tf: [le=L*8][hblk 16][ks 4][lane 64][8 bf16]; value = nw1[le][k=ks*32+q*8+j][h=16hblk+l15]
// -> k_mlp afr load is ONE contiguous 1KB per wave.
__global__ void k_trf1(const float* __restrict__ in, unsigned short* __restrict__ outp) {
  int c = blockIdx.x * 256 + threadIdx.x;      // 98304 chunks of 16B
  int le = c >> 12, hblk = (c >> 8) & 15, ks = (c >> 6) & 3, l = c & 63;
  int l15 = l & 15, q = l >> 4;
  const float* base = in + (size_t)le * 32768;
  unsigned short v[8];
#pragma unroll
  for (int j = 0; j < 8; ++j)
    v[j] = bf16_1(base[(ks * 32 + q * 8 + j) * 256 + hblk * 16 + l15]);
  uint4 pk;
  pk.x = (unsigned)v[0] | ((unsigned)v[1] << 16);
  pk.y = (unsigned)v[2] | ((unsigned)v[3] << 16);
  pk.z = (unsigned)v[4] | ((unsigned)v[5] << 16);
  pk.w = (unsigned)v[6] | ((unsigned)v[7] << 16);
  *(uint4*)&outp[(size_t)c * 8] = pk;
}

// w2tf: [le][dblk 8][ksh 8][lane 64][8]; value = nw2[le][h=ksh*32+q*8+j][d=16dblk+l15]
__global__ void k_trf2(const float* __restrict__ in, unsigned short* __restrict__ outp) {
  int c = blockIdx.x * 256 + threadIdx.x;      // 98304 chunks
  int le = c >> 12, dblk = (c >> 9) & 7, ksh = (c >> 6) & 7, l = c & 63;
  int l15 = l & 15, q = l >> 4;
  const float* base = in + (size_t)le * 32768;
  unsigned short v[8];
#pragma unroll
  for (int j = 0; j < 8; ++j)
    v[j] = bf16_1(base[(ksh * 32 + q * 8 + j) * 128 + dblk * 16 + l15]);
  uint4 pk;
  pk.x = (unsigned)v[0] | ((unsigned)v[1] << 16);
  pk.y = (unsigned)v[2] | ((unsigned)v[3] << 16);
  pk.z = (unsigned)v[4] | ((unsigned)v[5] << 16);
  pk.w = (unsigned)v[6] | ((unsigned)v[7] << 16);
  *(uint4*)&outp[(size_t)c * 8] = pk;
}

// =============== dist + per-graph sum / sumsq ===============
__global__ void k_dist(const float* __restrict__ pos, const int* __restrict__ src,
                       const int* __restrict__ dst, float* __restrict__ dist,
                       float* __restrict__ gsum, float* __restrict__ gsq) {
  int e = blockIdx.x * 256 + threadIdx.x;
  int s = src[e], t = dst[e];
  float dx = pos[3 * s]     - pos[3 * t];
  float dy = pos[3 * s + 1] - pos[3 * t + 1];
  float dz = pos[3 * s + 2] - pos[3 * t + 2];
  float d = sqrtf(dx * dx + dy * dy + dz * dz);
  dist[e] = d;
  float s1 = d, s2 = d * d;
  for (int o = 32; o; o >>= 1) { s1 += __shfl_down(s1, o); s2 += __shfl_down(s2, o); }
  __shared__ float r1[4], r2[4];
  int w = threadIdx.x >> 6;
  if ((threadIdx.x & 63) == 0) { r1[w] = s1; r2[w] = s2; }
  __syncthreads();
  if (threadIdx.x == 0) {
    int g = e >> 14;
    atomicAdd(&gsum[g], r1[0] + r1[1] + r1[2] + r1[3]);
    atomicAdd(&gsq[g],  r2[0] + r2[1] + r2[2] + r2[3]);
  }
}

__global__ void k_efin(const float* __restrict__ gsum, const float* __restrict__ gsq,
                       const float* __restrict__ dnw, const float* __restrict__ dnb,
                       const float* __restrict__ dnms, float* __restrict__ ga, float* __restrict__ gb) {
  int g = threadIdx.x;
  if (g < NG) {
    float ms = dnms[0];
    float mean = gsum[g] * (1.f / EPG);
    float var = gsq[g] * (1.f / EPG) - (2.f * ms - ms * ms) * mean * mean;
    float a = dnw[0] * rsqrtf(var + 1e-5f);
    ga[g] = a;
    gb[g] = dnb[0] - a * ms * mean;
  }
}

__global__ void k_embed(const float4* __restrict__ emb, const int* __restrict__ at,
                        float4* __restrict__ h) {
  int gid = blockIdx.x * 256 + threadIdx.x;
  int i = gid >> 5, q = gid & 31;
  h[gid] = emb[at[i] * 32 + q];
}

// =============== fused edge MoE + aggregation ===============
// grid NE/1024 = 512, block 256. Block b owns edges [1024b,1024b+1024) = nodes [32b,32b+32).
// Phase A: edge-MoE router (identical math to old k_edge) -> eaw in LDS (never global).
// Phase B: per-node aggregation (identical math to old k_agg) -> aggf in FRAGMENT order:
//   aggf[x][ntile=i>>4][ks=k>>5][lane=(i&15)+16*((k>>3)&3)][byte (k&7)*2]
__global__ __launch_bounds__(256) void k_ea(
    const float* __restrict__ dist, const float* __restrict__ ga, const float* __restrict__ gb,
    const float* __restrict__ ew1, const float* __restrict__ eb1,
    const float* __restrict__ ew2, const float* __restrict__ eb2,
    const float* __restrict__ h, const int* __restrict__ src,
    unsigned short* __restrict__ aggf, float* __restrict__ part) {
  __shared__ float w1s[EHID], b1s[EHID];
  __shared__ __align__(16) float w2s[EHID * NEXPT];
  __shared__ float b2s[NEXPT];
  __shared__ __align__(16) float sw[1024][NEXPT];  // 32KB eaw for this block's edges
  __shared__ int ssrc[1024];
  __shared__ float ps[4][NEXPT];
  int t = threadIdx.x;
  if (t < EHID) { w1s[t] = ew1[t]; b1s[t] = eb1[t]; }
  if (t < NEXPT) b2s[t] = eb2[t];
  for (int j = t; j < EHID * NEXPT; j += 256) w2s[j] = ew2[j];
  const int e0b = blockIdx.x * 1024;
#pragma unroll
  for (int k = 0; k < 4; ++k) ssrc[t + 256 * k] = src[e0b + t + 256 * k];
  __syncthreads();

  // ---- phase A: router (math identical to k_edge) ----
  int e0 = e0b + t * 4;
  float4 dv = *(const float4*)&dist[e0];
  float dd[4] = {dv.x, dv.y, dv.z, dv.w};
  int g = e0 >> 14;
  float gav = ga[g], gbv = gb[g];
  float a0[4], ewv[4];
#pragma unroll
  for (int j = 0; j < 4; ++j) {
    a0[j] = gav * dd[j] + gbv;
    ewv[j] = (10.0f - dd[j]) * 0.1f;
  }
  float acc[4][NEXPT];
#pragma unroll
  for (int j = 0; j < 4; ++j)
#pragma unroll
    for (int x = 0; x < NEXPT; ++x) acc[j][x] = b2s[x];
  for (int k = 0; k < EHID; ++k) {
    float w1k = w1s[k], b1k = b1s[k];
    float hk[4];
#pragma unroll
    for (int j = 0; j < 4; ++j) hk[j] = fmaxf(a0[j] * w1k + b1k, 0.f);
    float4 wa = *(const float4*)&w2s[k * 8];
    float4 wb = *(const float4*)&w2s[k * 8 + 4];
    float ww[8] = {wa.x, wa.y, wa.z, wa.w, wb.x, wb.y, wb.z, wb.w};
#pragma unroll
    for (int j = 0; j < 4; ++j)
#pragma unroll
      for (int x = 0; x < NEXPT; ++x) acc[j][x] += hk[j] * ww[x];
  }
  float esum[NEXPT] = {0, 0, 0, 0, 0, 0, 0, 0};
#pragma unroll
  for (int j = 0; j < 4; ++j) {
    float m = acc[j][0];
#pragma unroll
    for (int x = 1; x < NEXPT; ++x) m = fmaxf(m, acc[j][x]);
    float p[NEXPT], s = 0.f;
#pragma unroll
    for (int x = 0; x < NEXPT; ++x) { p[x] = __expf(acc[j][x] - m); s += p[x]; }
    float inv = 1.f / s;
    float fw = ewv[j] * inv;
    float4 o0 = {p[0] * fw, p[1] * fw, p[2] * fw, p[3] * fw};
    float4 o1 = {p[4] * fw, p[5] * fw, p[6] * fw, p[7] * fw};
    *(float4*)&sw[t * 4 + j][0] = o0;
    *(float4*)&sw[t * 4 + j][4] = o1;
#pragma unroll
    for (int x = 0; x < NEXPT; ++x) esum[x] += p[x] * inv;
  }
  for (int o = 32; o; o >>= 1)
#pragma unroll
    for (int x = 0; x < NEXPT; ++x) esum[x] += __shfl_down(esum[x], o);
  int wv = t >> 6;
  if ((t & 63) == 0)
#pragma unroll
    for (int x = 0; x < NEXPT; ++x) ps[wv][x] = esum[x];
  __syncthreads();  // sw + ps ready
  if (t < NEXPT) part[blockIdx.x * NEXPT + t] = ps[0][t] + ps[1][t] + ps[2][t] + ps[3][t];

  // ---- phase B: aggregation (math identical to k_agg), 4 node-octets ----
  const int s8 = t >> 5, lane = t & 31;
  for (int oct = 0; oct < 4; ++oct) {
    int iloc = oct * 8 + s8;
    int i = blockIdx.x * 32 + iloc;
    f4 ac[NEXPT];
#pragma unroll
    for (int x = 0; x < NEXPT; ++x) ac[x] = (f4)0.f;
#pragma unroll 2
    for (int k = 0; k < DEG; ++k) {
      f4 hv = *(const f4*)&h[(size_t)ssrc[iloc * 32 + k] * 128 + lane * 4];
      f4 w0 = *(const f4*)&sw[iloc * 32 + k][0];
      f4 w1v = *(const f4*)&sw[iloc * 32 + k][4];
      float ww[8] = {w0[0], w0[1], w0[2], w0[3], w1v[0], w1v[1], w1v[2], w1v[3]};
#pragma unroll
      for (int x = 0; x < NEXPT; ++x) ac[x] += ww[x] * hv;
    }
#pragma unroll
    for (int x = 0; x < NEXPT; ++x) {
      uint2 pk;
      pk.x = bf16pair(ac[x][0], ac[x][1]);
      pk.y = bf16pair(ac[x][2], ac[x][3]);
      size_t off = ((((size_t)x * 1024 + (i >> 4)) * 4 + (lane >> 3)) * 64 +
                    ((i & 15) + 16 * ((lane >> 1) & 3))) * 16 + (lane & 1) * 8;
      *(uint2*)((char*)aggf + off) = pk;
    }
  }
}

// =============== MFMA expert MLP (round-10 structure; frag-ordered operand loads) ===============
// grid (NN/64, 2), block 256 (4 waves); blockIdx.y = expert group of 4.
// ALL global operand loads are now 1KB-contiguous per wave (frag-ordered layouts).
// LDS hid path, barriers (1/expert, double-buffered), accumulators: unchanged from round 10.
__global__ __launch_bounds__(256) void k_mlp(
    const unsigned short* __restrict__ aggf,  // frag order [8][1024][4][64][8]
    const unsigned short* __restrict__ w1tf,  // frag order [8][16][4][64][8] (per layer)
    const float* __restrict__ b1g,            // [8][256]
    const unsigned short* __restrict__ w2tf,  // frag order [8][8][8][64][8] (per layer)
    float* __restrict__ part) {               // [2][NN][128] f32 partials
  __shared__ unsigned short hid[2][64 * 256];
  char* hb = (char*)hid;
  const int t = threadIdx.x;
  const int w = t >> 6, t63 = t & 63;
  const int l15 = t & 15;
  const int q = (t & 63) >> 4;
  const int bx = blockIdx.x;
  const int i0 = bx * 64;
  const int x0 = blockIdx.y * 4;
  float* pout = part + (size_t)blockIdx.y * NN * 128;

  f4 acc2[2][4];
#pragma unroll
  for (int dt = 0; dt < 2; ++dt)
#pragma unroll
    for (int nt = 0; nt < 4; ++nt) acc2[dt][nt] = (f4)0.f;

  for (int xi = 0; xi < 4; ++xi) {
    const int x = x0 + xi;
    const int bufb = (xi & 1) * 32768;
    // ---- GEMM1: wave w covers h in [64w, 64w+64) ----
    f4 acc1[4][4];
#pragma unroll
    for (int ht = 0; ht < 4; ++ht) {
      f4 bb = *(const f4*)&b1g[x * 256 + 64 * w + 16 * ht + 4 * q];
#pragma unroll
      for (int nt = 0; nt < 4; ++nt) acc1[ht][nt] = bb;
    }
#pragma unroll
    for (int ks = 0; ks < 4; ++ks) {
      bh8 afr[4], bfr[4];
#pragma unroll
      for (int ht = 0; ht < 4; ++ht)
        afr[ht] = *(const bh8*)&w1tf[((((size_t)x * 16 + 4 * w + ht) * 4 + ks) * 64 + t63) * 8];
#pragma unroll
      for (int nt = 0; nt < 4; ++nt)
        bfr[nt] = *(const bh8*)&aggf[((((size_t)x * 1024 + bx * 4 + nt) * 4 + ks) * 64 + t63) * 8];
#pragma unroll
      for (int ht = 0; ht < 4; ++ht)
#pragma unroll
        for (int nt = 0; nt < 4; ++nt)
          acc1[ht][nt] = __builtin_amdgcn_mfma_f32_16x16x32_bf16(afr[ht], bfr[nt], acc1[ht][nt], 0, 0, 0);
    }
    // relu + pack -> swizzled LDS buffer (xi&1)  [unchanged]
#pragma unroll
    for (int ht = 0; ht < 4; ++ht)
#pragma unroll
      for (int nt = 0; nt < 4; ++nt) {
        int node = 16 * nt + l15;
        int h0 = 64 * w + 16 * ht + 4 * q;
        int byte0 = bufb + ((node * 512 + h0 * 2) ^ ((node & 7) << 4));
        *(unsigned int*)(hb + byte0) =
            bf16pair(fmaxf(acc1[ht][nt][0], 0.f), fmaxf(acc1[ht][nt][1], 0.f));
        *(unsigned int*)(hb + byte0 + 4) =
            bf16pair(fmaxf(acc1[ht][nt][2], 0.f), fmaxf(acc1[ht][nt][3], 0.f));
      }
    __syncthreads();
    // ---- GEMM2: wave w covers d in [32w, 32w+32) ----
#pragma unroll
    for (int ks = 0; ks < 8; ++ks) {
      bh8 a2[2], b2f[4];
#pragma unroll
      for (int dt = 0; dt < 2; ++dt)
        a2[dt] = *(const bh8*)&w2tf[((((size_t)x * 8 + 2 * w + dt) * 8 + ks) * 64 + t63) * 8];
#pragma unroll
      for (int nt = 0; nt < 4; ++nt) {
        int node = 16 * nt + l15;
        int byte0 = bufb + ((node * 512 + ks * 64 + q * 16) ^ ((node & 7) << 4));
        b2f[nt] = *(const bh8*)(hb + byte0);
      }
#pragma unroll
      for (int dt = 0; dt < 2; ++dt)
#pragma unroll
        for (int nt = 0; nt < 4; ++nt)
          acc2[dt][nt] = __builtin_amdgcn_mfma_f32_16x16x32_bf16(a2[dt], b2f[nt], acc2[dt][nt], 0, 0, 0);
    }
  }
  // store partial [unchanged]
#pragma unroll
  for (int dt = 0; dt < 2; ++dt)
#pragma unroll
    for (int nt = 0; nt < 4; ++nt)
      *(f4*)&pout[(size_t)(i0 + 16 * nt + l15) * 128 + 32 * w + 16 * dt + 4 * q] = acc2[dt][nt];
}

// =============== reduce partials + b2 ===============
__global__ void k_red(const float4* __restrict__ part, float4* __restrict__ outp,
                      const float* __restrict__ b2g) {
  int i = blockIdx.x * 256 + threadIdx.x;
  int d4 = i & 31;
  float4 b = make_float4(0.f, 0.f, 0.f, 0.f);
#pragma unroll
  for (int x = 0; x < NEXPT; ++x) {
    float4 bv = *(const float4*)&b2g[x * 128 + d4 * 4];
    b.x += bv.x; b.y += bv.y; b.z += bv.z; b.w += bv.w;
  }
  float4 a0 = part[i];
  float4 a1 = part[i + NN * 128 / 4];
  float4 r = {a0.x + a1.x + b.x, a0.y + a1.y + b.y, a0.z + a1.z + b.z, a0.w + a1.w + b.w};
  outp[i] = r;
}

// =============== node GraphNorm ===============
__global__ void k_gnr(const float* __restrict__ h, float* __restrict__ nsum, float* __restrict__ nsq) {
  int g = blockIdx.x, strip = blockIdx.y;
  int c = threadIdx.x;
  const float* base = h + ((size_t)g * NPG + strip * 64) * 128 + c;
  float s = 0.f, q = 0.f;
  for (int n = 0; n < 64; ++n) { float v = base[(size_t)n * 128]; s += v; q += v * v; }
  atomicAdd(&nsum[g * 128 + c], s);
  atomicAdd(&nsq[g * 128 + c], q);
}

// fused gnf+gna: compute affine from nsum/nsq inline, apply tanh. (same formulas/op order)
__global__ void k_gna(float* __restrict__ h, const float* __restrict__ nsum,
                      const float* __restrict__ nsq, const float* __restrict__ gw,
                      const float* __restrict__ gbv, const float* __restrict__ gms) {
  int gid = blockIdx.x * 256 + threadIdx.x;
  int i = gid >> 5, q = gid & 31;
  int g = i >> 9;
  float4 s1 = *(const float4*)&nsum[g * 128 + q * 4];
  float4 s2 = *(const float4*)&nsq[g * 128 + q * 4];
  float4 msv = *(const float4*)&gms[q * 4];
  float4 wvv = *(const float4*)&gw[q * 4];
  float4 bvv = *(const float4*)&gbv[q * 4];
  float4 v = *(float4*)&h[(size_t)gid * 4];
  float sa[4] = {s1.x, s1.y, s1.z, s1.w};
  float sq[4] = {s2.x, s2.y, s2.z, s2.w};
  float mm[4] = {msv.x, msv.y, msv.z, msv.w};
  float wa[4] = {wvv.x, wvv.y, wvv.z, wvv.w};
  float ba[4] = {bvv.x, bvv.y, bvv.z, bvv.w};
  float vv[4] = {v.x, v.y, v.z, v.w};
#pragma unroll
  for (int j = 0; j < 4; ++j) {
    float ms = mm[j];
    float mean = sa[j] * (1.f / NPG);
    float var = sq[j] * (1.f / NPG) - (2.f * ms - ms * ms) * mean * mean;
    float a = wa[j] * rsqrtf(var + 1e-5f);
    float b = ba[j] - a * ms * mean;
    vv[j] = tanhf(a * vv[j] + b);
  }
  v.x = vv[0]; v.y = vv[1]; v.z = vv[2]; v.w = vv[3];
  *(float4*)&h[(size_t)gid * 4] = v;
}

// =============== final pooling + routing loss ===============
__global__ void k_pool(const float* __restrict__ h, float* __restrict__ outp) {
  int g = blockIdx.x, t = threadIdx.x;
  const float4* base = (const float4*)(h + (size_t)g * NPG * 128);
  float s = 0.f;
  for (int p = 0; p < 64; ++p) { float4 v = base[p * 256 + t]; s += v.x + v.y + v.z + v.w; }
  for (int o = 32; o; o >>= 1) s += __shfl_down(s, o);
  __shared__ float r[4];
  if ((t & 63) == 0) r[t >> 6] = s;
  __syncthreads();
  if (t == 0) outp[g] = (r[0] + r[1] + r[2] + r[3]) * (1.f / (NPG * 128));
}

__global__ void k_lbl(const float* __restrict__ part, float* __restrict__ outp) {
  __shared__ float s[NL * NEXPT];
  int t = threadIdx.x;
  if (t < NL * NEXPT) {
    int l = t >> 3, x = t & 7;
    float acc = 0.f;
    for (int b = 0; b < 512; ++b) acc += part[(size_t)(l * 512 + b) * NEXPT + x];
    s[t] = acc;
  }
  __syncthreads();
  if (t == 0) {
    float lbl = 0.f;
    for (int j = 0; j < NL * NEXPT; ++j) { float m = s[j] * (1.f / NE); lbl += m * m; }
    outp[0] = lbl * ((float)NEXPT / NL) * 0.1f;
  }
}

// =============== launcher ===============
extern "C" void kernel_launch(void* const* d_in, const int* in_sizes, int n_in,
                              void* d_out, int out_size, void* d_ws, size_t ws_size,
                              hipStream_t stream) {
  (void)in_sizes; (void)n_in; (void)out_size; (void)ws_size;
  const float* pos  = (const float*)d_in[0];
  const float* emb  = (const float*)d_in[1];
  const float* ew1  = (const float*)d_in[2];
  const float* eb1  = (const float*)d_in[3];
  const float* ew2  = (const float*)d_in[4];
  const float* eb2  = (const float*)d_in[5];
  const float* nw1  = (const float*)d_in[6];
  const float* nb1  = (const float*)d_in[7];
  const float* nw2  = (const float*)d_in[8];
  const float* nb2  = (const float*)d_in[9];
  const float* gnw  = (const float*)d_in[10];
  const float* gnb  = (const float*)d_in[11];
  const float* gnms = (const float*)d_in[12];
  const float* dnw  = (const float*)d_in[13];
  const float* dnb  = (const float*)d_in[14];
  const float* dnms = (const float*)d_in[15];
  const int* atom   = (const int*)d_in[16];
  const int* eidx   = (const int*)d_in[17];
  float* out = (float*)d_out;

  char* wsb = (char*)d_ws;
  float* dist = (float*)wsb;                   wsb += sizeof(float) * NE;
  float* mpart = (float*)wsb;                  wsb += sizeof(float) * (size_t)2 * NN * 128;
  unsigned short* aggf = (unsigned short*)wsb; wsb += sizeof(short) * (size_t)8 * NN * 128;
  unsigned short* w1tf = (unsigned short*)wsb; wsb += sizeof(short) * (size_t)NL * 8 * 256 * 128;
  unsigned short* w2tf = (unsigned short*)wsb; wsb += sizeof(short) * (size_t)NL * 8 * 256 * 128;
  float* hA   = (float*)wsb;                   wsb += sizeof(float) * (size_t)NN * 128;
  float* hB   = (float*)wsb;                   wsb += sizeof(float) * (size_t)NN * 128;
  float* gsum = (float*)wsb;                   wsb += sizeof(float) * NG;
  float* gsq  = (float*)wsb;                   wsb += sizeof(float) * NG;
  float* ga   = (float*)wsb;                   wsb += sizeof(float) * NG;
  float* gb   = (float*)wsb;                   wsb += sizeof(float) * NG;
  float* nsum = (float*)wsb;                   wsb += sizeof(float) * NG * 128;
  float* nsq  = (float*)wsb;                   wsb += sizeof(float) * NG * 128;
  float* part = (float*)wsb;                   wsb += sizeof(float) * (size_t)NL * 512 * NEXPT;

  const int* srcA = eidx;
  const int* dstA = eidx + NE;

  k_zero<<<1, 256, 0, stream>>>((float4*)gsum, 16);  // gsum+gsq
  // frag-order weight swizzle (all layers; per-layer slab = 262144 shorts)
  k_trf1<<<384, 256, 0, stream>>>(nw1, w1tf);
  k_trf2<<<384, 256, 0, stream>>>(nw2, w2tf);
  k_dist<<<NE / 256, 256, 0, stream>>>(pos, srcA, dstA, dist, gsum, gsq);
  k_efin<<<1, 64, 0, stream>>>(gsum, gsq, dnw, dnb, dnms, ga, gb);
  k_embed<<<NN * 32 / 256, 256, 0, stream>>>((const float4*)emb, atom, (float4*)hA);

  float* hcur = hA;
  float* hnxt = hB;
  for (int l = 0; l < NL; ++l) {
    k_ea<<<NE / 1024, 256, 0, stream>>>(dist, ga, gb, ew1 + l * EHID, eb1 + l * EHID,
                                        ew2 + (size_t)l * EHID * NEXPT, eb2 + l * NEXPT,
                                        hcur, srcA, aggf, part + (size_t)l * 512 * NEXPT);
    {
      dim3 gm(NN / 64, 2);
      k_mlp<<<gm, 256, 0, stream>>>(aggf,
                                    w1tf + (size_t)l * 262144,
                                    nb1 + (size_t)l * 8 * 256,
                                    w2tf + (size_t)l * 262144,
                                    mpart);
    }
    k_red<<<NN * 128 / 4 / 256, 256, 0, stream>>>((const float4*)mpart, (float4*)hnxt,
                                                  nb2 + (size_t)l * 8 * 128);
    if (l + 1 < NL) {
      k_zero<<<8, 256, 0, stream>>>((float4*)nsum, 2048);  // nsum+nsq
      dim3 gr(NG, 8);
      k_gnr<<<gr, 128, 0, stream>>>(hnxt, nsum, nsq);
      k_gna<<<NN * 32 / 256, 256, 0, stream>>>(hnxt, nsum, nsq,
                                               gnw + l * 128, gnb + l * 128, gnms + l * 128);
    }
    float* tmp = hcur; hcur = hnxt; hnxt = tmp;
  }
  k_pool<<<NG, 256, 0, stream>>>(hcur, out);
  k_lbl<<<1, 64, 0, stream>>>(part, out + NG);
}